// Round 10
// baseline (204.553 us; speedup 1.0000x reference)
//
#include <hip/hip_runtime.h>

#define TB 256
#define NGRP 8            // XCDs on MI355X
#define NB_P 256          // partition blocks
#define TBP 256           // partition block threads
#define NBKT 256          // dst-range buckets (32 per XCD)
#define SORT_T 1024
#define STG_CAP 14336     // LDS staging entries in k_bsort (56 KB)

typedef int      i4v __attribute__((ext_vector_type(4)));
typedef float    f4v __attribute__((ext_vector_type(4)));
typedef _Float16 h4v __attribute__((ext_vector_type(4)));
typedef _Float16 h8v __attribute__((ext_vector_type(8)));

static __device__ __forceinline__ float leaky(float x) {
  return x > 0.f ? x : 0.2f * x;
}

// ================= CSR build: 256-bucket partition + per-bucket LDS sort =================

// A1: 4 sub-histograms (one per wave) to cut same-address LDS atomic serialization.
__global__ void k_bcount(const int* __restrict__ dstA, int* __restrict__ cnt,
                         int E4, int E, unsigned M, int CH4) {
  __shared__ int lc[4 * NBKT];
  for (int i = threadIdx.x; i < 4 * NBKT; i += TBP) lc[i] = 0;
  __syncthreads();
  int* lcw = lc + (threadIdx.x >> 6) * NBKT;
  const int bstart = blockIdx.x * CH4;
  const int bend = min(E4, bstart + CH4);
  const i4v* d4 = reinterpret_cast<const i4v*>(dstA);
  for (int i = bstart + threadIdx.x; i < bend; i += TBP) {
    i4v d = __builtin_nontemporal_load(&d4[i]);
#pragma unroll
    for (int k = 0; k < 4; ++k) atomicAdd(&lcw[__umulhi((unsigned)d[k], M)], 1);
  }
  if (blockIdx.x == NB_P - 1) {
    for (int t = E4 * 4 + threadIdx.x; t < E; t += TBP)
      atomicAdd(&lcw[__umulhi((unsigned)dstA[t], M)], 1);
  }
  __syncthreads();
  for (int b = threadIdx.x; b < NBKT; b += TBP)
    cnt[b * NB_P + blockIdx.x] = lc[b] + lc[NBKT + b] + lc[2 * NBKT + b] + lc[3 * NBKT + b];
}

__global__ void k_bscan1(const int* __restrict__ cnt, int* __restrict__ off,
                         int* __restrict__ colTotal) {
  __shared__ int sh[NB_P];
  const int t = threadIdx.x;
  const int b = blockIdx.x;
  int v = cnt[b * NB_P + t];
  sh[t] = v;
  __syncthreads();
  for (int o = 1; o < NB_P; o <<= 1) {
    int u = (t >= o) ? sh[t - o] : 0;
    __syncthreads();
    sh[t] += u;
    __syncthreads();
  }
  off[b * NB_P + t] = sh[t] - v;
  if (t == NB_P - 1) colTotal[b] = sh[t];
}

__global__ void k_bscan2(const int* __restrict__ colTotal, int* __restrict__ bucketBase) {
  __shared__ int sh[NBKT];
  const int t = threadIdx.x;
  int v = colTotal[t];
  sh[t] = v;
  __syncthreads();
  for (int o = 1; o < NBKT; o <<= 1) {
    int u = (t >= o) ? sh[t - o] : 0;
    __syncthreads();
    sh[t] += u;
    __syncthreads();
  }
  bucketBase[t] = sh[t] - v;
  if (t == NBKT - 1) bucketBase[NBKT] = sh[t];
}

__global__ void k_bscatter(const int* __restrict__ srcA, const int* __restrict__ dstA,
                           const int* __restrict__ off, const int* __restrict__ bucketBase,
                           int* __restrict__ epk, int E4, int E, unsigned M, int R, int CH4) {
  __shared__ int lcur[NBKT];
  for (int i = threadIdx.x; i < NBKT; i += TBP)
    lcur[i] = bucketBase[i] + off[i * NB_P + blockIdx.x];
  __syncthreads();
  const int bstart = blockIdx.x * CH4;
  const int bend = min(E4, bstart + CH4);
  const i4v* d4 = reinterpret_cast<const i4v*>(dstA);
  const i4v* s4 = reinterpret_cast<const i4v*>(srcA);
  for (int i = bstart + threadIdx.x; i < bend; i += TBP) {
    i4v d = __builtin_nontemporal_load(&d4[i]);
    i4v sv = __builtin_nontemporal_load(&s4[i]);
#pragma unroll
    for (int k = 0; k < 4; ++k) {
      int dd = d[k];
      int b = __umulhi((unsigned)dd, M);
      int pos = atomicAdd(&lcur[b], 1);
      epk[pos] = ((dd - b * R) << 17) | sv[k];
    }
  }
  if (blockIdx.x == NB_P - 1) {
    for (int t = E4 * 4 + threadIdx.x; t < E; t += TBP) {
      int dd = dstA[t];
      int b = __umulhi((unsigned)dd, M);
      int pos = atomicAdd(&lcur[b], 1);
      epk[pos] = ((dd - b * R) << 17) | srcA[t];
    }
  }
}

// B: per-bucket counting sort; scatter into LDS staging, coalesced global write.
__global__ void k_bsort(const int* __restrict__ epk, const int* __restrict__ bucketBase,
                        int* __restrict__ rowStart, int* __restrict__ colIdx,
                        int N, int R, int E) {
  __shared__ int sc[512];
  __shared__ int stg[STG_CAP];
  const int b = (blockIdx.x & (NGRP - 1)) * (NBKT / NGRP) + (blockIdx.x >> 3);
  const int lo = bucketBase[b], hi = bucketBase[b + 1];
  const int cnt = hi - lo;
  const int nodeLo = b * R;
  const int nN = min(R, N - nodeLo);
  const int t = threadIdx.x;
  if (t < 512) sc[t] = 0;
  __syncthreads();
  for (int i = lo + t; i < hi; i += SORT_T) {
    int pk = __builtin_nontemporal_load(&epk[i]);
    atomicAdd(&sc[pk >> 17], 1);
  }
  __syncthreads();
  int own = (t < 512) ? sc[t] : 0;
  for (int o = 1; o < 512; o <<= 1) {
    int u = (t < 512 && t >= o) ? sc[t - o] : 0;
    __syncthreads();
    if (t < 512) sc[t] += u;
    __syncthreads();
  }
  if (t < nN) rowStart[nodeLo + t] = lo + sc[t] - own;
  if (b == NBKT - 1 && t == 0) rowStart[N] = E;
  if (t < 512) sc[t] -= own;  // exclusive bucket-local cursors
  __syncthreads();
  if (cnt <= STG_CAP) {
    for (int i = lo + t; i < hi; i += SORT_T) {
      int pk = epk[i];
      int pos = atomicAdd(&sc[pk >> 17], 1);
      stg[pos] = pk & 0x1FFFF;
    }
    __syncthreads();
    for (int i = t; i < cnt; i += SORT_T) colIdx[lo + i] = stg[i];  // coalesced
  } else {
    for (int i = lo + t; i < hi; i += SORT_T) {
      int pk = epk[i];
      int pos = lo + atomicAdd(&sc[pk >> 17], 1);
      colIdx[pos] = pk & 0x1FFFF;
    }
  }
}

// ================= node transform (layer 1): SPLIT threads/node =================

template <int IN, int H, int C, int SPLIT, bool NT>
__global__ void k_node(const float* __restrict__ xin, const float* __restrict__ W,
                       const float* __restrict__ a_src, const float* __restrict__ a_dst,
                       _Float16* __restrict__ hout, float* __restrict__ as_,
                       float* __restrict__ ad_, int N) {
  constexpr int OUT = H * C;
  constexpr int PIN4 = IN / SPLIT / 4;
  constexpr int NPB = TB / SPLIT;
  __shared__ float Ws[IN * OUT];
  __shared__ float As[OUT], Ad[OUT];
  for (int i = threadIdx.x; i < IN * OUT; i += blockDim.x) Ws[i] = W[i];
  if (threadIdx.x < OUT) {
    As[threadIdx.x] = a_src[threadIdx.x];
    Ad[threadIdx.x] = a_dst[threadIdx.x];
  }
  __syncthreads();
  const int j = threadIdx.x & (SPLIT - 1);
  const int n = blockIdx.x * NPB + threadIdx.x / SPLIT;
  if (n >= N) return;
  float acc[OUT];
#pragma unroll
  for (int q = 0; q < OUT; ++q) acc[q] = 0.f;
  const f4v* x4 = reinterpret_cast<const f4v*>(xin + (size_t)n * IN + j * (IN / SPLIT));
#pragma unroll
  for (int k4 = 0; k4 < PIN4; ++k4) {
    f4v xv = NT ? __builtin_nontemporal_load(&x4[k4]) : x4[k4];
    const int kb = j * (IN / SPLIT) + 4 * k4;
#pragma unroll
    for (int q = 0; q < OUT; ++q) {
      acc[q] += xv[0] * Ws[(kb + 0) * OUT + q];
      acc[q] += xv[1] * Ws[(kb + 1) * OUT + q];
      acc[q] += xv[2] * Ws[(kb + 2) * OUT + q];
      acc[q] += xv[3] * Ws[(kb + 3) * OUT + q];
    }
  }
#pragma unroll
  for (int o = 1; o < SPLIT; o <<= 1) {
#pragma unroll
    for (int q = 0; q < OUT; ++q) acc[q] += __shfl_xor(acc[q], o);
  }
  constexpr int WCH = OUT / 4;
  if (j < WCH) {
    h4v v;
    v[0] = (_Float16)acc[4 * j + 0];
    v[1] = (_Float16)acc[4 * j + 1];
    v[2] = (_Float16)acc[4 * j + 2];
    v[3] = (_Float16)acc[4 * j + 3];
    reinterpret_cast<h4v*>(hout + (size_t)n * OUT)[j] = v;
  }
  if (j < H) {
    float ss = 0.f, dd = 0.f;
#pragma unroll
    for (int c = 0; c < C; ++c) {
      ss += acc[j * C + c] * As[j * C + c];
      dd += acc[j * C + c] * Ad[j * C + c];
    }
    as_[n * H + j] = ss;
    ad_[n * H + j] = dd;
  }
}

// ================= edge layer 1 + fused node transform 2 =================
// L=2 lanes x 16B h1 gathers, S=8 edge-split (1 chunk/thread typical).

__global__ void __launch_bounds__(TB, 8)
k_edge12(const int* __restrict__ rowStart, const int* __restrict__ colIdx,
         const _Float16* __restrict__ h1, const float* __restrict__ as_,
         const float* __restrict__ ad_, const float* __restrict__ b1,
         const float* __restrict__ W2, const float* __restrict__ as2w,
         const float* __restrict__ ad2w, _Float16* __restrict__ h2,
         float* __restrict__ as2, float* __restrict__ ad2, int N, int R8) {
  constexpr int L = 2, S = 8, LS = 16, NPB = TB / LS;
  __shared__ float Ws2[128], A2s[8], A2d[8], B1s[16];
  if (threadIdx.x < 128) Ws2[threadIdx.x] = W2[threadIdx.x];
  if (threadIdx.x < 8) {
    A2s[threadIdx.x] = as2w[threadIdx.x];
    A2d[threadIdx.x] = ad2w[threadIdx.x];
  }
  if (threadIdx.x < 16) B1s[threadIdx.x] = b1[threadIdx.x];
  __syncthreads();
  const int g = blockIdx.x & (NGRP - 1);
  const int lb = blockIdx.x / NGRP;
  const int lane = threadIdx.x % LS;
  const int sub = lane >> 1;
  const int j = lane & 1;
  const int n = g * R8 + lb * NPB + threadIdx.x / LS;
  const int nEnd = min((g + 1) * R8, N);
  if (n >= nEnd) return;
  const float adv = ad_[n * 2 + j];
  const int start = rowStart[n];
  const int end = rowStart[n + 1];
  float s = 0.f, acc[8];
#pragma unroll
  for (int q = 0; q < 8; ++q) acc[q] = 0.f;
  if (sub == 0) {  // self-loop
    float p = __expf(leaky(as_[n * 2 + j] + adv));
    h8v a0 = reinterpret_cast<const h8v*>(h1 + (size_t)n * 16)[j];
    s = p;
#pragma unroll
    for (int q = 0; q < 8; ++q) acc[q] = p * (float)a0[q];
  }
  const int base = start & ~3;
  const int nch = (end - base + 3) >> 2;
  for (int t = sub; t < nch; t += S) {
    const int i0 = base + 4 * t;
    i4v cv = *reinterpret_cast<const i4v*>(colIdx + i0);
#pragma unroll
    for (int k = 0; k < 4; ++k) {
      const bool ok = (i0 + k >= start) && (i0 + k < end);
      const int src = ok ? cv[k] : n;
      h8v hv = reinterpret_cast<const h8v*>(h1 + (size_t)src * 16)[j];
      float e = as_[src * 2 + j];
      float p = ok ? __expf(leaky(e + adv)) : 0.f;
      s += p;
#pragma unroll
      for (int q = 0; q < 8; ++q) acc[q] += p * (float)hv[q];
    }
  }
#pragma unroll
  for (int off = L; off < LS; off <<= 1) {
    s += __shfl_xor(s, off);
#pragma unroll
    for (int q = 0; q < 8; ++q) acc[q] += __shfl_xor(acc[q], off);
  }
  if (sub == 0) {
    float inv = 1.f / (s + 1e-16f);
    float o1v[8];
#pragma unroll
    for (int q = 0; q < 8; ++q) o1v[q] = fmaxf(acc[q] * inv + B1s[j * 8 + q], 0.f);
    float h2p[8];
#pragma unroll
    for (int q = 0; q < 8; ++q) {
      float tacc = 0.f;
#pragma unroll
      for (int c = 0; c < 8; ++c) tacc += o1v[c] * Ws2[(j * 8 + c) * 8 + q];
      h2p[q] = tacc;
    }
    float h2f[8];
#pragma unroll
    for (int q = 0; q < 8; ++q) h2f[q] = h2p[q] + __shfl_xor(h2p[q], 1);
    h4v v;
#pragma unroll
    for (int q = 0; q < 4; ++q) v[q] = (_Float16)h2f[j * 4 + q];
    reinterpret_cast<h4v*>(h2 + (size_t)n * 8)[j] = v;
    float ss = 0.f, dd = 0.f;
#pragma unroll
    for (int c = 0; c < 4; ++c) {
      ss += h2f[j * 4 + c] * A2s[j * 4 + c];
      dd += h2f[j * 4 + c] * A2d[j * 4 + c];
    }
    as2[n * 2 + j] = ss;
    ad2[n * 2 + j] = dd;
  }
}

// ================= edge layer 2 + fused node transform 3 =================

__global__ void __launch_bounds__(TB, 8)
k_edge23(const int* __restrict__ rowStart, const int* __restrict__ colIdx,
         const _Float16* __restrict__ h2, const float* __restrict__ as_,
         const float* __restrict__ ad_, const float* __restrict__ b2,
         const float* __restrict__ W3, const float* __restrict__ as3w,
         const float* __restrict__ ad3w, _Float16* __restrict__ h3,
         float* __restrict__ as3, float* __restrict__ ad3, int N, int R8) {
  constexpr int L = 2, S = 8, LS = 16, NPB = TB / LS;
  __shared__ float Ws3[32], A3s[4], A3d[4], B2s[8];
  if (threadIdx.x < 32) Ws3[threadIdx.x] = W3[threadIdx.x];
  if (threadIdx.x < 4) {
    A3s[threadIdx.x] = as3w[threadIdx.x];
    A3d[threadIdx.x] = ad3w[threadIdx.x];
  }
  if (threadIdx.x < 8) B2s[threadIdx.x] = b2[threadIdx.x];
  __syncthreads();
  const int g = blockIdx.x & (NGRP - 1);
  const int lb = blockIdx.x / NGRP;
  const int lane = threadIdx.x % LS;
  const int sub = lane >> 1;
  const int j = lane & 1;
  const int n = g * R8 + lb * NPB + threadIdx.x / LS;
  const int nEnd = min((g + 1) * R8, N);
  if (n >= nEnd) return;
  const float adv = ad_[n * 2 + j];
  const int start = rowStart[n];
  const int end = rowStart[n + 1];
  float s = 0.f, acc[4];
#pragma unroll
  for (int q = 0; q < 4; ++q) acc[q] = 0.f;
  if (sub == 0) {
    float p = __expf(leaky(as_[n * 2 + j] + adv));
    h4v a0 = reinterpret_cast<const h4v*>(h2 + (size_t)n * 8)[j];
    s = p;
#pragma unroll
    for (int q = 0; q < 4; ++q) acc[q] = p * (float)a0[q];
  }
  const int base = start & ~3;
  const int nch = (end - base + 3) >> 2;
  for (int t = sub; t < nch; t += S) {
    const int i0 = base + 4 * t;
    i4v cv = *reinterpret_cast<const i4v*>(colIdx + i0);
#pragma unroll
    for (int k = 0; k < 4; ++k) {
      const bool ok = (i0 + k >= start) && (i0 + k < end);
      const int src = ok ? cv[k] : n;
      h4v hv = reinterpret_cast<const h4v*>(h2 + (size_t)src * 8)[j];
      float e = as_[src * 2 + j];
      float p = ok ? __expf(leaky(e + adv)) : 0.f;
      s += p;
#pragma unroll
      for (int q = 0; q < 4; ++q) acc[q] += p * (float)hv[q];
    }
  }
#pragma unroll
  for (int off = L; off < LS; off <<= 1) {
    s += __shfl_xor(s, off);
#pragma unroll
    for (int q = 0; q < 4; ++q) acc[q] += __shfl_xor(acc[q], off);
  }
  if (sub == 0) {
    float inv = 1.f / (s + 1e-16f);
    float o2v[4];
#pragma unroll
    for (int q = 0; q < 4; ++q) o2v[q] = fmaxf(acc[q] * inv + B2s[j * 4 + q], 0.f);
    float h3p[4];
#pragma unroll
    for (int q = 0; q < 4; ++q) {
      float tacc = 0.f;
#pragma unroll
      for (int c = 0; c < 4; ++c) tacc += o2v[c] * Ws3[(j * 4 + c) * 4 + q];
      h3p[q] = tacc;
    }
    float h3f[4];
#pragma unroll
    for (int q = 0; q < 4; ++q) h3f[q] = h3p[q] + __shfl_xor(h3p[q], 1);
    if (j == 0) {
      h4v v;
#pragma unroll
      for (int q = 0; q < 4; ++q) v[q] = (_Float16)h3f[q];
      reinterpret_cast<h4v*>(h3)[n] = v;
      float ss = 0.f, dd = 0.f;
#pragma unroll
      for (int c = 0; c < 4; ++c) {
        ss += h3f[c] * A3s[c];
        dd += h3f[c] * A3d[c];
      }
      as3[n] = ss;
      ad3[n] = dd;
    }
  }
}

// ================= edge layer 3 + fused classifier; S=16, chunked =================

__global__ void __launch_bounds__(TB, 8)
k_edge3(const int* __restrict__ rowStart, const int* __restrict__ colIdx,
        const _Float16* __restrict__ hfeat, const float* __restrict__ as_,
        const float* __restrict__ ad_, const float* __restrict__ b3,
        const float* __restrict__ Wc, const float* __restrict__ bc,
        float* __restrict__ out, int N, int R8) {
  constexpr int S = 16;
  constexpr int NPB = TB / S;
  const int g = blockIdx.x & (NGRP - 1);
  const int lb = blockIdx.x / NGRP;
  const int sub = threadIdx.x % S;
  const int n = g * R8 + lb * NPB + threadIdx.x / S;
  const int nEnd = min((g + 1) * R8, N);
  if (n >= nEnd) return;
  const float adv = ad_[n];
  const int start = rowStart[n];
  const int end = rowStart[n + 1];
  float s = 0.f, acc0 = 0.f, acc1 = 0.f, acc2 = 0.f, acc3 = 0.f;
  if (sub == 0) {
    float p = __expf(leaky(as_[n] + adv));
    h4v a0 = reinterpret_cast<const h4v*>(hfeat)[n];
    s = p;
    acc0 = p * (float)a0[0];
    acc1 = p * (float)a0[1];
    acc2 = p * (float)a0[2];
    acc3 = p * (float)a0[3];
  }
  const int base = start & ~3;
  const int nch = (end - base + 3) >> 2;
  for (int t = sub; t < nch; t += S) {
    const int i0 = base + 4 * t;
    i4v cv = *reinterpret_cast<const i4v*>(colIdx + i0);
#pragma unroll
    for (int k = 0; k < 4; ++k) {
      const bool ok = (i0 + k >= start) && (i0 + k < end);
      const int src = ok ? cv[k] : n;
      h4v hv = reinterpret_cast<const h4v*>(hfeat)[src];
      float e = as_[src];
      float p = ok ? __expf(leaky(e + adv)) : 0.f;
      s += p;
      acc0 += p * (float)hv[0];
      acc1 += p * (float)hv[1];
      acc2 += p * (float)hv[2];
      acc3 += p * (float)hv[3];
    }
  }
#pragma unroll
  for (int off = 1; off < S; off <<= 1) {
    s += __shfl_xor(s, off);
    acc0 += __shfl_xor(acc0, off);
    acc1 += __shfl_xor(acc1, off);
    acc2 += __shfl_xor(acc2, off);
    acc3 += __shfl_xor(acc3, off);
  }
  if (sub == 0) {
    float inv = 1.f / (s + 1e-16f);
    float o0 = acc0 * inv + b3[0];
    float o1 = acc1 * inv + b3[1];
    float o2 = acc2 * inv + b3[2];
    float o3 = acc3 * inv + b3[3];
    float2 r;
    r.x = o0 * Wc[0] + o1 * Wc[2] + o2 * Wc[4] + o3 * Wc[6] + bc[0];
    r.y = o0 * Wc[1] + o1 * Wc[3] + o2 * Wc[5] + o3 * Wc[7] + bc[1];
    reinterpret_cast<float2*>(out)[n] = r;
  }
}

// ================= launch =================

extern "C" void kernel_launch(void* const* d_in, const int* in_sizes, int n_in,
                              void* d_out, int out_size, void* d_ws, size_t ws_size,
                              hipStream_t stream) {
  const float* x    = (const float*)d_in[0];
  const int*   ei   = (const int*)d_in[1];
  const float* W1   = (const float*)d_in[2];
  const float* as1w = (const float*)d_in[3];
  const float* ad1w = (const float*)d_in[4];
  const float* b1   = (const float*)d_in[5];
  const float* W2   = (const float*)d_in[6];
  const float* as2w = (const float*)d_in[7];
  const float* ad2w = (const float*)d_in[8];
  const float* b2   = (const float*)d_in[9];
  const float* W3   = (const float*)d_in[10];
  const float* as3w = (const float*)d_in[11];
  const float* ad3w = (const float*)d_in[12];
  const float* b3   = (const float*)d_in[13];
  const float* Wc   = (const float*)d_in[14];
  const float* bc   = (const float*)d_in[15];
  float* out = (float*)d_out;

  const int N = in_sizes[0] / 128;
  const int E = in_sizes[1] / 2;
  const int* srcA = ei;
  const int* dstA = ei + E;

  char* p = (char*)d_ws;
  auto alloc = [&](size_t bytes) -> void* {
    void* r = (void*)p;
    p += (bytes + 255) & ~(size_t)255;
    return r;
  };
  int* cnt        = (int*)alloc((size_t)NBKT * NB_P * 4);
  int* off        = (int*)alloc((size_t)NBKT * NB_P * 4);
  int* colTotal   = (int*)alloc(NBKT * 4);
  int* bucketBase = (int*)alloc((NBKT + 1) * 4);
  int* rowStart   = (int*)alloc((size_t)(N + 1) * 4);
  int* epk        = (int*)alloc((size_t)E * 4);
  int* colIdx     = (int*)alloc((size_t)E * 4 + 256);
  _Float16* h1 = (_Float16*)alloc((size_t)N * 16 * 2);
  float* as1 = (float*)alloc((size_t)N * 2 * 4);
  float* ad1 = (float*)alloc((size_t)N * 2 * 4);
  _Float16* h2 = (_Float16*)alloc((size_t)N * 8 * 2);
  float* as2 = (float*)alloc((size_t)N * 2 * 4);
  float* ad2 = (float*)alloc((size_t)N * 2 * 4);
  _Float16* h3 = (_Float16*)alloc((size_t)N * 4 * 2);
  float* as3 = (float*)alloc((size_t)N * 4);
  float* ad3 = (float*)alloc((size_t)N * 4);

  const int R   = (N + NBKT - 1) / NBKT;                       // nodes per bucket (391)
  const unsigned M = (unsigned)(((1ULL << 32) + R - 1) / R);   // exact /R via __umulhi
  const int R8  = R * (NBKT / NGRP);                           // nodes per XCD (12512)
  const int E4  = E >> 2;
  const int CH4 = (E4 + NB_P - 1) / NB_P;

  // CSR build (no global atomics; coalesced colIdx write)
  k_bcount<<<NB_P, TBP, 0, stream>>>(dstA, cnt, E4, E, M, CH4);
  k_bscan1<<<NBKT, NB_P, 0, stream>>>(cnt, off, colTotal);
  k_bscan2<<<1, NBKT, 0, stream>>>(colTotal, bucketBase);
  k_bscatter<<<NB_P, TBP, 0, stream>>>(srcA, dstA, off, bucketBase, epk, E4, E, M, R, CH4);
  k_bsort<<<NBKT, SORT_T, 0, stream>>>(epk, bucketBase, rowStart, colIdx, N, R, E);

  const int nb1 = (N + (TB / 4) - 1) / (TB / 4);
  const int ge16 = NGRP * ((R8 + (TB / 16) - 1) / (TB / 16));  // LS=16 -> 16 nodes/block

  k_node<128, 2, 8, 4, true><<<nb1, TB, 0, stream>>>(x, W1, as1w, ad1w, h1, as1, ad1, N);
  k_edge12<<<ge16, TB, 0, stream>>>(rowStart, colIdx, h1, as1, ad1, b1, W2, as2w, ad2w,
                                    h2, as2, ad2, N, R8);
  k_edge23<<<ge16, TB, 0, stream>>>(rowStart, colIdx, h2, as2, ad2, b2, W3, as3w, ad3w,
                                    h3, as3, ad3, N, R8);
  k_edge3<<<ge16, TB, 0, stream>>>(rowStart, colIdx, h3, as3, ad3, b3, Wc, bc, out, N, R8);
}

// Round 11
// 201.844 us; speedup vs baseline: 1.0134x; 1.0134x over previous
//
#include <hip/hip_runtime.h>

#define TB 256
#define NGRP 8            // XCDs on MI355X
#define NB_P 512          // partition blocks
#define TBP 256           // partition block threads
#define NBKT 256          // dst-range buckets (32 per XCD)
#define SORT_T 1024
#define STG_CAP 14336     // LDS staging entries in k_bsort (56 KB)
#define STG2_CAP 6400     // LDS staging entries in k_bscatter (25.6 KB)

typedef int      i4v __attribute__((ext_vector_type(4)));
typedef float    f4v __attribute__((ext_vector_type(4)));
typedef _Float16 h4v __attribute__((ext_vector_type(4)));
typedef _Float16 h8v __attribute__((ext_vector_type(8)));

static __device__ __forceinline__ float leaky(float x) {
  return x > 0.f ? x : 0.2f * x;
}

// ================= CSR build: 256-bucket partition + per-bucket LDS sort =================

// A1: 4 sub-histograms (one per wave) to cut same-address LDS atomic serialization.
__global__ void k_bcount(const int* __restrict__ dstA, int* __restrict__ cnt,
                         int E4, int E, unsigned M, int CH4) {
  __shared__ int lc[4 * NBKT];
  for (int i = threadIdx.x; i < 4 * NBKT; i += TBP) lc[i] = 0;
  __syncthreads();
  int* lcw = lc + (threadIdx.x >> 6) * NBKT;
  const int bstart = blockIdx.x * CH4;
  const int bend = min(E4, bstart + CH4);
  const i4v* d4 = reinterpret_cast<const i4v*>(dstA);
  for (int i = bstart + threadIdx.x; i < bend; i += TBP) {
    i4v d = __builtin_nontemporal_load(&d4[i]);
#pragma unroll
    for (int k = 0; k < 4; ++k) atomicAdd(&lcw[__umulhi((unsigned)d[k], M)], 1);
  }
  if (blockIdx.x == NB_P - 1) {
    for (int t = E4 * 4 + threadIdx.x; t < E; t += TBP)
      atomicAdd(&lcw[__umulhi((unsigned)dstA[t], M)], 1);
  }
  __syncthreads();
  for (int b = threadIdx.x; b < NBKT; b += TBP)
    cnt[b * NB_P + blockIdx.x] = lc[b] + lc[NBKT + b] + lc[2 * NBKT + b] + lc[3 * NBKT + b];
}

// A2a: per-bucket exclusive scan over blocks (grid = NBKT, block = NB_P threads).
__global__ void k_bscan1(const int* __restrict__ cnt, int* __restrict__ off,
                         int* __restrict__ colTotal) {
  __shared__ int sh[NB_P];
  const int t = threadIdx.x;
  const int b = blockIdx.x;
  int v = cnt[b * NB_P + t];
  sh[t] = v;
  __syncthreads();
  for (int o = 1; o < NB_P; o <<= 1) {
    int u = (t >= o) ? sh[t - o] : 0;
    __syncthreads();
    sh[t] += u;
    __syncthreads();
  }
  off[b * NB_P + t] = sh[t] - v;
  if (t == NB_P - 1) colTotal[b] = sh[t];
}

// A2b: exclusive scan of bucket totals -> bucketBase[NBKT+1].
__global__ void k_bscan2(const int* __restrict__ colTotal, int* __restrict__ bucketBase) {
  __shared__ int sh[NBKT];
  const int t = threadIdx.x;
  int v = colTotal[t];
  sh[t] = v;
  __syncthreads();
  for (int o = 1; o < NBKT; o <<= 1) {
    int u = (t >= o) ? sh[t - o] : 0;
    __syncthreads();
    sh[t] += u;
    __syncthreads();
  }
  bucketBase[t] = sh[t] - v;
  if (t == NBKT - 1) bucketBase[NBKT] = sh[t];
}

// A3: LDS-staged scatter. Edges appended to per-bucket LDS lists (layout from this
// block's cnt column), then flushed to global bucket segments COALESCED.
__global__ void k_bscatter(const int* __restrict__ srcA, const int* __restrict__ dstA,
                           const int* __restrict__ cnt, const int* __restrict__ off,
                           const int* __restrict__ bucketBase, int* __restrict__ epk,
                           int E4, int E, unsigned M, int R, int CH4) {
  __shared__ int loff[NBKT + 1];
  __shared__ int lcur[NBKT];
  __shared__ int gbase[NBKT];
  __shared__ int stg[STG2_CAP];
  const int t = threadIdx.x;
  {  // exclusive scan of this block's per-bucket counts (NBKT values, TBP==NBKT threads)
    int v = cnt[t * NB_P + blockIdx.x];
    loff[t] = v;
    __syncthreads();
    for (int o = 1; o < NBKT; o <<= 1) {
      int u = (t >= o) ? loff[t - o] : 0;
      __syncthreads();
      loff[t] += u;
      __syncthreads();
    }
    int incl = loff[t];
    __syncthreads();
    loff[t] = incl - v;           // exclusive
    lcur[t] = incl - v;
    if (t == NBKT - 1) loff[NBKT] = incl;
    gbase[t] = bucketBase[t] + off[t * NB_P + blockIdx.x];
  }
  __syncthreads();
  const int bstart = blockIdx.x * CH4;
  const int bend = min(E4, bstart + CH4);
  const i4v* d4 = reinterpret_cast<const i4v*>(dstA);
  const i4v* s4 = reinterpret_cast<const i4v*>(srcA);
  for (int i = bstart + t; i < bend; i += TBP) {
    i4v d = __builtin_nontemporal_load(&d4[i]);
    i4v sv = __builtin_nontemporal_load(&s4[i]);
#pragma unroll
    for (int k = 0; k < 4; ++k) {
      int dd = d[k];
      int b = __umulhi((unsigned)dd, M);
      int pos = atomicAdd(&lcur[b], 1);
      stg[pos] = ((dd - b * R) << 17) | sv[k];
    }
  }
  if (blockIdx.x == NB_P - 1) {
    for (int i = E4 * 4 + t; i < E; i += TBP) {
      int dd = dstA[i];
      int b = __umulhi((unsigned)dd, M);
      int pos = atomicAdd(&lcur[b], 1);
      stg[pos] = ((dd - b * R) << 17) | srcA[i];
    }
  }
  __syncthreads();
  const int total = loff[NBKT];
  for (int i = t; i < total; i += TBP) {
    int loQ = 0, hiQ = NBKT;  // find b: loff[b] <= i < loff[b+1]
#pragma unroll
    for (int it = 0; it < 8; ++it) {
      int mid = (loQ + hiQ) >> 1;
      if (loff[mid] <= i) loQ = mid; else hiQ = mid;
    }
    epk[gbase[loQ] + (i - loff[loQ])] = stg[i];  // coalesced runs per bucket
  }
}

// B: per-bucket counting sort; scatter into LDS staging, coalesced global write.
__global__ void k_bsort(const int* __restrict__ epk, const int* __restrict__ bucketBase,
                        int* __restrict__ rowStart, int* __restrict__ colIdx,
                        int N, int R, int E) {
  __shared__ int sc[512];
  __shared__ int stg[STG_CAP];
  const int b = (blockIdx.x & (NGRP - 1)) * (NBKT / NGRP) + (blockIdx.x >> 3);
  const int lo = bucketBase[b], hi = bucketBase[b + 1];
  const int cnt = hi - lo;
  const int nodeLo = b * R;
  const int nN = min(R, N - nodeLo);
  const int t = threadIdx.x;
  if (t < 512) sc[t] = 0;
  __syncthreads();
  for (int i = lo + t; i < hi; i += SORT_T) {
    int pk = __builtin_nontemporal_load(&epk[i]);
    atomicAdd(&sc[pk >> 17], 1);
  }
  __syncthreads();
  int own = (t < 512) ? sc[t] : 0;
  for (int o = 1; o < 512; o <<= 1) {
    int u = (t < 512 && t >= o) ? sc[t - o] : 0;
    __syncthreads();
    if (t < 512) sc[t] += u;
    __syncthreads();
  }
  if (t < nN) rowStart[nodeLo + t] = lo + sc[t] - own;
  if (b == NBKT - 1 && t == 0) rowStart[N] = E;
  if (t < 512) sc[t] -= own;  // exclusive bucket-local cursors
  __syncthreads();
  if (cnt <= STG_CAP) {
    for (int i = lo + t; i < hi; i += SORT_T) {
      int pk = epk[i];
      int pos = atomicAdd(&sc[pk >> 17], 1);
      stg[pos] = pk & 0x1FFFF;
    }
    __syncthreads();
    for (int i = t; i < cnt; i += SORT_T) colIdx[lo + i] = stg[i];  // coalesced
  } else {
    for (int i = lo + t; i < hi; i += SORT_T) {
      int pk = epk[i];
      int pos = lo + atomicAdd(&sc[pk >> 17], 1);
      colIdx[pos] = pk & 0x1FFFF;
    }
  }
}

// ================= node transform (layer 1): SPLIT threads/node =================

template <int IN, int H, int C, int SPLIT, bool NT>
__global__ void k_node(const float* __restrict__ xin, const float* __restrict__ W,
                       const float* __restrict__ a_src, const float* __restrict__ a_dst,
                       _Float16* __restrict__ hout, float* __restrict__ as_,
                       float* __restrict__ ad_, int N) {
  constexpr int OUT = H * C;
  constexpr int PIN4 = IN / SPLIT / 4;
  constexpr int NPB = TB / SPLIT;
  __shared__ float Ws[IN * OUT];
  __shared__ float As[OUT], Ad[OUT];
  for (int i = threadIdx.x; i < IN * OUT; i += blockDim.x) Ws[i] = W[i];
  if (threadIdx.x < OUT) {
    As[threadIdx.x] = a_src[threadIdx.x];
    Ad[threadIdx.x] = a_dst[threadIdx.x];
  }
  __syncthreads();
  const int j = threadIdx.x & (SPLIT - 1);
  const int n = blockIdx.x * NPB + threadIdx.x / SPLIT;
  if (n >= N) return;
  float acc[OUT];
#pragma unroll
  for (int q = 0; q < OUT; ++q) acc[q] = 0.f;
  const f4v* x4 = reinterpret_cast<const f4v*>(xin + (size_t)n * IN + j * (IN / SPLIT));
#pragma unroll
  for (int k4 = 0; k4 < PIN4; ++k4) {
    f4v xv = NT ? __builtin_nontemporal_load(&x4[k4]) : x4[k4];
    const int kb = j * (IN / SPLIT) + 4 * k4;
#pragma unroll
    for (int q = 0; q < OUT; ++q) {
      acc[q] += xv[0] * Ws[(kb + 0) * OUT + q];
      acc[q] += xv[1] * Ws[(kb + 1) * OUT + q];
      acc[q] += xv[2] * Ws[(kb + 2) * OUT + q];
      acc[q] += xv[3] * Ws[(kb + 3) * OUT + q];
    }
  }
#pragma unroll
  for (int o = 1; o < SPLIT; o <<= 1) {
#pragma unroll
    for (int q = 0; q < OUT; ++q) acc[q] += __shfl_xor(acc[q], o);
  }
  constexpr int WCH = OUT / 4;
  if (j < WCH) {
    h4v v;
    v[0] = (_Float16)acc[4 * j + 0];
    v[1] = (_Float16)acc[4 * j + 1];
    v[2] = (_Float16)acc[4 * j + 2];
    v[3] = (_Float16)acc[4 * j + 3];
    reinterpret_cast<h4v*>(hout + (size_t)n * OUT)[j] = v;
  }
  if (j < H) {
    float ss = 0.f, dd = 0.f;
#pragma unroll
    for (int c = 0; c < C; ++c) {
      ss += acc[j * C + c] * As[j * C + c];
      dd += acc[j * C + c] * Ad[j * C + c];
    }
    as_[n * H + j] = ss;
    ad_[n * H + j] = dd;
  }
}

// ================= edge layer 1 + fused node transform 2 =================
// L=2 lanes x 16B h1 gathers, S=4. Interior chunks take an UNMASKED fast path.

__global__ void __launch_bounds__(TB, 8)
k_edge12(const int* __restrict__ rowStart, const int* __restrict__ colIdx,
         const _Float16* __restrict__ h1, const float* __restrict__ as_,
         const float* __restrict__ ad_, const float* __restrict__ b1,
         const float* __restrict__ W2, const float* __restrict__ as2w,
         const float* __restrict__ ad2w, _Float16* __restrict__ h2,
         float* __restrict__ as2, float* __restrict__ ad2, int N, int R8) {
  constexpr int L = 2, S = 4, LS = 8, NPB = TB / LS;
  __shared__ float Ws2[128], A2s[8], A2d[8], B1s[16];
  if (threadIdx.x < 128) Ws2[threadIdx.x] = W2[threadIdx.x];
  if (threadIdx.x < 8) {
    A2s[threadIdx.x] = as2w[threadIdx.x];
    A2d[threadIdx.x] = ad2w[threadIdx.x];
  }
  if (threadIdx.x < 16) B1s[threadIdx.x] = b1[threadIdx.x];
  __syncthreads();
  const int g = blockIdx.x & (NGRP - 1);
  const int lb = blockIdx.x / NGRP;
  const int lane = threadIdx.x % LS;
  const int sub = lane >> 1;
  const int j = lane & 1;
  const int n = g * R8 + lb * NPB + threadIdx.x / LS;
  const int nEnd = min((g + 1) * R8, N);
  if (n >= nEnd) return;
  const float adv = ad_[n * 2 + j];
  const int start = rowStart[n];
  const int end = rowStart[n + 1];
  float s = 0.f, acc[8];
#pragma unroll
  for (int q = 0; q < 8; ++q) acc[q] = 0.f;
  if (sub == 0) {  // self-loop
    float p = __expf(leaky(as_[n * 2 + j] + adv));
    h8v a0 = reinterpret_cast<const h8v*>(h1 + (size_t)n * 16)[j];
    s = p;
#pragma unroll
    for (int q = 0; q < 8; ++q) acc[q] = p * (float)a0[q];
  }
  const int base = start & ~3;
  const int nch = (end - base + 3) >> 2;
  for (int t = sub; t < nch; t += S) {
    const int i0 = base + 4 * t;
    i4v cv = *reinterpret_cast<const i4v*>(colIdx + i0);
    if (i0 >= start && i0 + 4 <= end) {  // interior: no masks
#pragma unroll
      for (int k = 0; k < 4; ++k) {
        const int src = cv[k];
        h8v hv = reinterpret_cast<const h8v*>(h1 + (size_t)src * 16)[j];
        float p = __expf(leaky(as_[src * 2 + j] + adv));
        s += p;
#pragma unroll
        for (int q = 0; q < 8; ++q) acc[q] += p * (float)hv[q];
      }
    } else {  // boundary chunk
#pragma unroll
      for (int k = 0; k < 4; ++k) {
        const bool ok = (i0 + k >= start) && (i0 + k < end);
        const int src = ok ? cv[k] : n;
        h8v hv = reinterpret_cast<const h8v*>(h1 + (size_t)src * 16)[j];
        float p = ok ? __expf(leaky(as_[src * 2 + j] + adv)) : 0.f;
        s += p;
#pragma unroll
        for (int q = 0; q < 8; ++q) acc[q] += p * (float)hv[q];
      }
    }
  }
#pragma unroll
  for (int off = L; off < LS; off <<= 1) {
    s += __shfl_xor(s, off);
#pragma unroll
    for (int q = 0; q < 8; ++q) acc[q] += __shfl_xor(acc[q], off);
  }
  if (sub == 0) {
    float inv = 1.f / (s + 1e-16f);
    float o1v[8];
#pragma unroll
    for (int q = 0; q < 8; ++q) o1v[q] = fmaxf(acc[q] * inv + B1s[j * 8 + q], 0.f);
    float h2p[8];
#pragma unroll
    for (int q = 0; q < 8; ++q) {
      float tacc = 0.f;
#pragma unroll
      for (int c = 0; c < 8; ++c) tacc += o1v[c] * Ws2[(j * 8 + c) * 8 + q];
      h2p[q] = tacc;
    }
    float h2f[8];
#pragma unroll
    for (int q = 0; q < 8; ++q) h2f[q] = h2p[q] + __shfl_xor(h2p[q], 1);
    h4v v;
#pragma unroll
    for (int q = 0; q < 4; ++q) v[q] = (_Float16)h2f[j * 4 + q];
    reinterpret_cast<h4v*>(h2 + (size_t)n * 8)[j] = v;
    float ss = 0.f, dd = 0.f;
#pragma unroll
    for (int c = 0; c < 4; ++c) {
      ss += h2f[j * 4 + c] * A2s[j * 4 + c];
      dd += h2f[j * 4 + c] * A2d[j * 4 + c];
    }
    as2[n * 2 + j] = ss;
    ad2[n * 2 + j] = dd;
  }
}

// ================= edge layer 2 + fused node transform 3 =================

__global__ void __launch_bounds__(TB, 8)
k_edge23(const int* __restrict__ rowStart, const int* __restrict__ colIdx,
         const _Float16* __restrict__ h2, const float* __restrict__ as_,
         const float* __restrict__ ad_, const float* __restrict__ b2,
         const float* __restrict__ W3, const float* __restrict__ as3w,
         const float* __restrict__ ad3w, _Float16* __restrict__ h3,
         float* __restrict__ as3, float* __restrict__ ad3, int N, int R8) {
  constexpr int L = 2, S = 4, LS = 8, NPB = TB / LS;
  __shared__ float Ws3[32], A3s[4], A3d[4], B2s[8];
  if (threadIdx.x < 32) Ws3[threadIdx.x] = W3[threadIdx.x];
  if (threadIdx.x < 4) {
    A3s[threadIdx.x] = as3w[threadIdx.x];
    A3d[threadIdx.x] = ad3w[threadIdx.x];
  }
  if (threadIdx.x < 8) B2s[threadIdx.x] = b2[threadIdx.x];
  __syncthreads();
  const int g = blockIdx.x & (NGRP - 1);
  const int lb = blockIdx.x / NGRP;
  const int lane = threadIdx.x % LS;
  const int sub = lane >> 1;
  const int j = lane & 1;
  const int n = g * R8 + lb * NPB + threadIdx.x / LS;
  const int nEnd = min((g + 1) * R8, N);
  if (n >= nEnd) return;
  const float adv = ad_[n * 2 + j];
  const int start = rowStart[n];
  const int end = rowStart[n + 1];
  float s = 0.f, acc[4];
#pragma unroll
  for (int q = 0; q < 4; ++q) acc[q] = 0.f;
  if (sub == 0) {
    float p = __expf(leaky(as_[n * 2 + j] + adv));
    h4v a0 = reinterpret_cast<const h4v*>(h2 + (size_t)n * 8)[j];
    s = p;
#pragma unroll
    for (int q = 0; q < 4; ++q) acc[q] = p * (float)a0[q];
  }
  const int base = start & ~3;
  const int nch = (end - base + 3) >> 2;
  for (int t = sub; t < nch; t += S) {
    const int i0 = base + 4 * t;
    i4v cv = *reinterpret_cast<const i4v*>(colIdx + i0);
    if (i0 >= start && i0 + 4 <= end) {
#pragma unroll
      for (int k = 0; k < 4; ++k) {
        const int src = cv[k];
        h4v hv = reinterpret_cast<const h4v*>(h2 + (size_t)src * 8)[j];
        float p = __expf(leaky(as_[src * 2 + j] + adv));
        s += p;
#pragma unroll
        for (int q = 0; q < 4; ++q) acc[q] += p * (float)hv[q];
      }
    } else {
#pragma unroll
      for (int k = 0; k < 4; ++k) {
        const bool ok = (i0 + k >= start) && (i0 + k < end);
        const int src = ok ? cv[k] : n;
        h4v hv = reinterpret_cast<const h4v*>(h2 + (size_t)src * 8)[j];
        float p = ok ? __expf(leaky(as_[src * 2 + j] + adv)) : 0.f;
        s += p;
#pragma unroll
        for (int q = 0; q < 4; ++q) acc[q] += p * (float)hv[q];
      }
    }
  }
#pragma unroll
  for (int off = L; off < LS; off <<= 1) {
    s += __shfl_xor(s, off);
#pragma unroll
    for (int q = 0; q < 4; ++q) acc[q] += __shfl_xor(acc[q], off);
  }
  if (sub == 0) {
    float inv = 1.f / (s + 1e-16f);
    float o2v[4];
#pragma unroll
    for (int q = 0; q < 4; ++q) o2v[q] = fmaxf(acc[q] * inv + B2s[j * 4 + q], 0.f);
    float h3p[4];
#pragma unroll
    for (int q = 0; q < 4; ++q) {
      float tacc = 0.f;
#pragma unroll
      for (int c = 0; c < 4; ++c) tacc += o2v[c] * Ws3[(j * 4 + c) * 4 + q];
      h3p[q] = tacc;
    }
    float h3f[4];
#pragma unroll
    for (int q = 0; q < 4; ++q) h3f[q] = h3p[q] + __shfl_xor(h3p[q], 1);
    if (j == 0) {
      h4v v;
#pragma unroll
      for (int q = 0; q < 4; ++q) v[q] = (_Float16)h3f[q];
      reinterpret_cast<h4v*>(h3)[n] = v;
      float ss = 0.f, dd = 0.f;
#pragma unroll
      for (int c = 0; c < 4; ++c) {
        ss += h3f[c] * A3s[c];
        dd += h3f[c] * A3d[c];
      }
      as3[n] = ss;
      ad3[n] = dd;
    }
  }
}

// ================= edge layer 3 + fused classifier; S=8, chunked =================

__global__ void __launch_bounds__(TB, 8)
k_edge3(const int* __restrict__ rowStart, const int* __restrict__ colIdx,
        const _Float16* __restrict__ hfeat, const float* __restrict__ as_,
        const float* __restrict__ ad_, const float* __restrict__ b3,
        const float* __restrict__ Wc, const float* __restrict__ bc,
        float* __restrict__ out, int N, int R8) {
  constexpr int S = 8;
  constexpr int NPB = TB / S;
  const int g = blockIdx.x & (NGRP - 1);
  const int lb = blockIdx.x / NGRP;
  const int sub = threadIdx.x % S;
  const int n = g * R8 + lb * NPB + threadIdx.x / S;
  const int nEnd = min((g + 1) * R8, N);
  if (n >= nEnd) return;
  const float adv = ad_[n];
  const int start = rowStart[n];
  const int end = rowStart[n + 1];
  float s = 0.f, acc0 = 0.f, acc1 = 0.f, acc2 = 0.f, acc3 = 0.f;
  if (sub == 0) {
    float p = __expf(leaky(as_[n] + adv));
    h4v a0 = reinterpret_cast<const h4v*>(hfeat)[n];
    s = p;
    acc0 = p * (float)a0[0];
    acc1 = p * (float)a0[1];
    acc2 = p * (float)a0[2];
    acc3 = p * (float)a0[3];
  }
  const int base = start & ~3;
  const int nch = (end - base + 3) >> 2;
  for (int t = sub; t < nch; t += S) {
    const int i0 = base + 4 * t;
    i4v cv = *reinterpret_cast<const i4v*>(colIdx + i0);
    if (i0 >= start && i0 + 4 <= end) {
#pragma unroll
      for (int k = 0; k < 4; ++k) {
        const int src = cv[k];
        h4v hv = reinterpret_cast<const h4v*>(hfeat)[src];
        float p = __expf(leaky(as_[src] + adv));
        s += p;
        acc0 += p * (float)hv[0];
        acc1 += p * (float)hv[1];
        acc2 += p * (float)hv[2];
        acc3 += p * (float)hv[3];
      }
    } else {
#pragma unroll
      for (int k = 0; k < 4; ++k) {
        const bool ok = (i0 + k >= start) && (i0 + k < end);
        const int src = ok ? cv[k] : n;
        h4v hv = reinterpret_cast<const h4v*>(hfeat)[src];
        float p = ok ? __expf(leaky(as_[src] + adv)) : 0.f;
        s += p;
        acc0 += p * (float)hv[0];
        acc1 += p * (float)hv[1];
        acc2 += p * (float)hv[2];
        acc3 += p * (float)hv[3];
      }
    }
  }
#pragma unroll
  for (int off = 1; off < S; off <<= 1) {
    s += __shfl_xor(s, off);
    acc0 += __shfl_xor(acc0, off);
    acc1 += __shfl_xor(acc1, off);
    acc2 += __shfl_xor(acc2, off);
    acc3 += __shfl_xor(acc3, off);
  }
  if (sub == 0) {
    float inv = 1.f / (s + 1e-16f);
    float o0 = acc0 * inv + b3[0];
    float o1 = acc1 * inv + b3[1];
    float o2 = acc2 * inv + b3[2];
    float o3 = acc3 * inv + b3[3];
    float2 r;
    r.x = o0 * Wc[0] + o1 * Wc[2] + o2 * Wc[4] + o3 * Wc[6] + bc[0];
    r.y = o0 * Wc[1] + o1 * Wc[3] + o2 * Wc[5] + o3 * Wc[7] + bc[1];
    reinterpret_cast<float2*>(out)[n] = r;
  }
}

// ================= launch =================

extern "C" void kernel_launch(void* const* d_in, const int* in_sizes, int n_in,
                              void* d_out, int out_size, void* d_ws, size_t ws_size,
                              hipStream_t stream) {
  const float* x    = (const float*)d_in[0];
  const int*   ei   = (const int*)d_in[1];
  const float* W1   = (const float*)d_in[2];
  const float* as1w = (const float*)d_in[3];
  const float* ad1w = (const float*)d_in[4];
  const float* b1   = (const float*)d_in[5];
  const float* W2   = (const float*)d_in[6];
  const float* as2w = (const float*)d_in[7];
  const float* ad2w = (const float*)d_in[8];
  const float* b2   = (const float*)d_in[9];
  const float* W3   = (const float*)d_in[10];
  const float* as3w = (const float*)d_in[11];
  const float* ad3w = (const float*)d_in[12];
  const float* b3   = (const float*)d_in[13];
  const float* Wc   = (const float*)d_in[14];
  const float* bc   = (const float*)d_in[15];
  float* out = (float*)d_out;

  const int N = in_sizes[0] / 128;
  const int E = in_sizes[1] / 2;
  const int* srcA = ei;
  const int* dstA = ei + E;

  char* p = (char*)d_ws;
  auto alloc = [&](size_t bytes) -> void* {
    void* r = (void*)p;
    p += (bytes + 255) & ~(size_t)255;
    return r;
  };
  int* cnt        = (int*)alloc((size_t)NBKT * NB_P * 4);
  int* off        = (int*)alloc((size_t)NBKT * NB_P * 4);
  int* colTotal   = (int*)alloc(NBKT * 4);
  int* bucketBase = (int*)alloc((NBKT + 1) * 4);
  int* rowStart   = (int*)alloc((size_t)(N + 1) * 4);
  int* epk        = (int*)alloc((size_t)E * 4);
  int* colIdx     = (int*)alloc((size_t)E * 4 + 256);
  _Float16* h1 = (_Float16*)alloc((size_t)N * 16 * 2);
  float* as1 = (float*)alloc((size_t)N * 2 * 4);
  float* ad1 = (float*)alloc((size_t)N * 2 * 4);
  _Float16* h2 = (_Float16*)alloc((size_t)N * 8 * 2);
  float* as2 = (float*)alloc((size_t)N * 2 * 4);
  float* ad2 = (float*)alloc((size_t)N * 2 * 4);
  _Float16* h3 = (_Float16*)alloc((size_t)N * 4 * 2);
  float* as3 = (float*)alloc((size_t)N * 4);
  float* ad3 = (float*)alloc((size_t)N * 4);

  const int R   = (N + NBKT - 1) / NBKT;                       // nodes per bucket (391)
  const unsigned M = (unsigned)(((1ULL << 32) + R - 1) / R);   // exact /R via __umulhi
  const int R8  = R * (NBKT / NGRP);                           // nodes per XCD (12512)
  const int E4  = E >> 2;
  const int CH4 = (E4 + NB_P - 1) / NB_P;

  // CSR build (no global atomics; coalesced epk and colIdx writes)
  k_bcount<<<NB_P, TBP, 0, stream>>>(dstA, cnt, E4, E, M, CH4);
  k_bscan1<<<NBKT, NB_P, 0, stream>>>(cnt, off, colTotal);
  k_bscan2<<<1, NBKT, 0, stream>>>(colTotal, bucketBase);
  k_bscatter<<<NB_P, TBP, 0, stream>>>(srcA, dstA, cnt, off, bucketBase, epk, E4, E, M, R, CH4);
  k_bsort<<<NBKT, SORT_T, 0, stream>>>(epk, bucketBase, rowStart, colIdx, N, R, E);

  const int nb1 = (N + (TB / 4) - 1) / (TB / 4);
  const int ge8 = NGRP * ((R8 + (TB / 8) - 1) / (TB / 8));  // LS=8 -> 32 nodes/block

  k_node<128, 2, 8, 4, true><<<nb1, TB, 0, stream>>>(x, W1, as1w, ad1w, h1, as1, ad1, N);
  k_edge12<<<ge8, TB, 0, stream>>>(rowStart, colIdx, h1, as1, ad1, b1, W2, as2w, ad2w,
                                   h2, as2, ad2, N, R8);
  k_edge23<<<ge8, TB, 0, stream>>>(rowStart, colIdx, h2, as2, ad2, b2, W3, as3w, ad3w,
                                   h3, as3, ad3, N, R8);
  k_edge3<<<ge8, TB, 0, stream>>>(rowStart, colIdx, h3, as3, ad3, b3, Wc, bc, out, N, R8);
}

// Round 12
// 177.896 us; speedup vs baseline: 1.1498x; 1.1346x over previous
//
#include <hip/hip_runtime.h>

#define TB 256
#define NGRP 8            // XCDs on MI355X
#define NB_P 512          // partition blocks
#define TBP 256           // partition block threads
#define NBKT 256          // dst-range buckets (32 per XCD)
#define SORT_T 1024
#define STG_CAP 14336     // LDS staging entries in k_bsort (56 KB)
#define STG2_CAP 6400     // LDS staging entries in k_bscatter (25.6 KB)

typedef int      i4v __attribute__((ext_vector_type(4)));
typedef float    f4v __attribute__((ext_vector_type(4)));
typedef _Float16 h4v __attribute__((ext_vector_type(4)));
typedef _Float16 h8v __attribute__((ext_vector_type(8)));

// Packed gather records: one cache line fetch per edge.
struct __align__(16) Rec2 { _Float16 h[8]; float as[2]; float pad[2]; };  // 32 B
struct __align__(16) Rec3 { _Float16 h[4]; float as; float pad; };        // 16 B

static __device__ __forceinline__ float leaky(float x) {
  return x > 0.f ? x : 0.2f * x;
}

// ================= CSR build: 256-bucket partition + per-bucket LDS sort =================

// A1: 4 sub-histograms (one per wave) to cut same-address LDS atomic serialization.
__global__ void k_bcount(const int* __restrict__ dstA, int* __restrict__ cnt,
                         int E4, int E, unsigned M, int CH4) {
  __shared__ int lc[4 * NBKT];
  for (int i = threadIdx.x; i < 4 * NBKT; i += TBP) lc[i] = 0;
  __syncthreads();
  int* lcw = lc + (threadIdx.x >> 6) * NBKT;
  const int bstart = blockIdx.x * CH4;
  const int bend = min(E4, bstart + CH4);
  const i4v* d4 = reinterpret_cast<const i4v*>(dstA);
  for (int i = bstart + threadIdx.x; i < bend; i += TBP) {
    i4v d = __builtin_nontemporal_load(&d4[i]);
#pragma unroll
    for (int k = 0; k < 4; ++k) atomicAdd(&lcw[__umulhi((unsigned)d[k], M)], 1);
  }
  if (blockIdx.x == NB_P - 1) {
    for (int t = E4 * 4 + threadIdx.x; t < E; t += TBP)
      atomicAdd(&lcw[__umulhi((unsigned)dstA[t], M)], 1);
  }
  __syncthreads();
  for (int b = threadIdx.x; b < NBKT; b += TBP)
    cnt[b * NB_P + blockIdx.x] = lc[b] + lc[NBKT + b] + lc[2 * NBKT + b] + lc[3 * NBKT + b];
}

// A2a: per-bucket exclusive scan over blocks (grid = NBKT, block = NB_P threads).
__global__ void k_bscan1(const int* __restrict__ cnt, int* __restrict__ off,
                         int* __restrict__ colTotal) {
  __shared__ int sh[NB_P];
  const int t = threadIdx.x;
  const int b = blockIdx.x;
  int v = cnt[b * NB_P + t];
  sh[t] = v;
  __syncthreads();
  for (int o = 1; o < NB_P; o <<= 1) {
    int u = (t >= o) ? sh[t - o] : 0;
    __syncthreads();
    sh[t] += u;
    __syncthreads();
  }
  off[b * NB_P + t] = sh[t] - v;
  if (t == NB_P - 1) colTotal[b] = sh[t];
}

// A2b: exclusive scan of bucket totals -> bucketBase[NBKT+1].
__global__ void k_bscan2(const int* __restrict__ colTotal, int* __restrict__ bucketBase) {
  __shared__ int sh[NBKT];
  const int t = threadIdx.x;
  int v = colTotal[t];
  sh[t] = v;
  __syncthreads();
  for (int o = 1; o < NBKT; o <<= 1) {
    int u = (t >= o) ? sh[t - o] : 0;
    __syncthreads();
    sh[t] += u;
    __syncthreads();
  }
  bucketBase[t] = sh[t] - v;
  if (t == NBKT - 1) bucketBase[NBKT] = sh[t];
}

// A3: LDS-staged scatter. Edges appended to per-bucket LDS lists (layout from this
// block's cnt column), then flushed to global bucket segments COALESCED.
__global__ void k_bscatter(const int* __restrict__ srcA, const int* __restrict__ dstA,
                           const int* __restrict__ cnt, const int* __restrict__ off,
                           const int* __restrict__ bucketBase, int* __restrict__ epk,
                           int E4, int E, unsigned M, int R, int CH4) {
  __shared__ int loff[NBKT + 1];
  __shared__ int lcur[NBKT];
  __shared__ int gbase[NBKT];
  __shared__ int stg[STG2_CAP];
  const int t = threadIdx.x;
  {
    int v = cnt[t * NB_P + blockIdx.x];
    loff[t] = v;
    __syncthreads();
    for (int o = 1; o < NBKT; o <<= 1) {
      int u = (t >= o) ? loff[t - o] : 0;
      __syncthreads();
      loff[t] += u;
      __syncthreads();
    }
    int incl = loff[t];
    __syncthreads();
    loff[t] = incl - v;
    lcur[t] = incl - v;
    if (t == NBKT - 1) loff[NBKT] = incl;
    gbase[t] = bucketBase[t] + off[t * NB_P + blockIdx.x];
  }
  __syncthreads();
  const int bstart = blockIdx.x * CH4;
  const int bend = min(E4, bstart + CH4);
  const i4v* d4 = reinterpret_cast<const i4v*>(dstA);
  const i4v* s4 = reinterpret_cast<const i4v*>(srcA);
  for (int i = bstart + t; i < bend; i += TBP) {
    i4v d = __builtin_nontemporal_load(&d4[i]);
    i4v sv = __builtin_nontemporal_load(&s4[i]);
#pragma unroll
    for (int k = 0; k < 4; ++k) {
      int dd = d[k];
      int b = __umulhi((unsigned)dd, M);
      int pos = atomicAdd(&lcur[b], 1);
      stg[pos] = ((dd - b * R) << 17) | sv[k];
    }
  }
  if (blockIdx.x == NB_P - 1) {
    for (int i = E4 * 4 + t; i < E; i += TBP) {
      int dd = dstA[i];
      int b = __umulhi((unsigned)dd, M);
      int pos = atomicAdd(&lcur[b], 1);
      stg[pos] = ((dd - b * R) << 17) | srcA[i];
    }
  }
  __syncthreads();
  const int total = loff[NBKT];
  for (int i = t; i < total; i += TBP) {
    int loQ = 0, hiQ = NBKT;
#pragma unroll
    for (int it = 0; it < 8; ++it) {
      int mid = (loQ + hiQ) >> 1;
      if (loff[mid] <= i) loQ = mid; else hiQ = mid;
    }
    epk[gbase[loQ] + (i - loff[loQ])] = stg[i];
  }
}

// B: per-bucket counting sort; scatter into LDS staging, coalesced global write.
__global__ void k_bsort(const int* __restrict__ epk, const int* __restrict__ bucketBase,
                        int* __restrict__ rowStart, int* __restrict__ colIdx,
                        int N, int R, int E) {
  __shared__ int sc[512];
  __shared__ int stg[STG_CAP];
  const int b = (blockIdx.x & (NGRP - 1)) * (NBKT / NGRP) + (blockIdx.x >> 3);
  const int lo = bucketBase[b], hi = bucketBase[b + 1];
  const int cnt = hi - lo;
  const int nodeLo = b * R;
  const int nN = min(R, N - nodeLo);
  const int t = threadIdx.x;
  if (t < 512) sc[t] = 0;
  __syncthreads();
  for (int i = lo + t; i < hi; i += SORT_T) {
    int pk = __builtin_nontemporal_load(&epk[i]);
    atomicAdd(&sc[pk >> 17], 1);
  }
  __syncthreads();
  int own = (t < 512) ? sc[t] : 0;
  for (int o = 1; o < 512; o <<= 1) {
    int u = (t < 512 && t >= o) ? sc[t - o] : 0;
    __syncthreads();
    if (t < 512) sc[t] += u;
    __syncthreads();
  }
  if (t < nN) rowStart[nodeLo + t] = lo + sc[t] - own;
  if (b == NBKT - 1 && t == 0) rowStart[N] = E;
  if (t < 512) sc[t] -= own;
  __syncthreads();
  if (cnt <= STG_CAP) {
    for (int i = lo + t; i < hi; i += SORT_T) {
      int pk = epk[i];
      int pos = atomicAdd(&sc[pk >> 17], 1);
      stg[pos] = pk & 0x1FFFF;
    }
    __syncthreads();
    for (int i = t; i < cnt; i += SORT_T) colIdx[lo + i] = stg[i];  // coalesced
  } else {
    for (int i = lo + t; i < hi; i += SORT_T) {
      int pk = epk[i];
      int pos = lo + atomicAdd(&sc[pk >> 17], 1);
      colIdx[pos] = pk & 0x1FFFF;
    }
  }
}

// ================= node transform (layer 1): SPLIT threads/node =================

template <int IN, int H, int C, int SPLIT, bool NT>
__global__ void k_node(const float* __restrict__ xin, const float* __restrict__ W,
                       const float* __restrict__ a_src, const float* __restrict__ a_dst,
                       _Float16* __restrict__ hout, float* __restrict__ as_,
                       float* __restrict__ ad_, int N) {
  constexpr int OUT = H * C;
  constexpr int PIN4 = IN / SPLIT / 4;
  constexpr int NPB = TB / SPLIT;
  __shared__ float Ws[IN * OUT];
  __shared__ float As[OUT], Ad[OUT];
  for (int i = threadIdx.x; i < IN * OUT; i += blockDim.x) Ws[i] = W[i];
  if (threadIdx.x < OUT) {
    As[threadIdx.x] = a_src[threadIdx.x];
    Ad[threadIdx.x] = a_dst[threadIdx.x];
  }
  __syncthreads();
  const int j = threadIdx.x & (SPLIT - 1);
  const int n = blockIdx.x * NPB + threadIdx.x / SPLIT;
  if (n >= N) return;
  float acc[OUT];
#pragma unroll
  for (int q = 0; q < OUT; ++q) acc[q] = 0.f;
  const f4v* x4 = reinterpret_cast<const f4v*>(xin + (size_t)n * IN + j * (IN / SPLIT));
#pragma unroll
  for (int k4 = 0; k4 < PIN4; ++k4) {
    f4v xv = NT ? __builtin_nontemporal_load(&x4[k4]) : x4[k4];
    const int kb = j * (IN / SPLIT) + 4 * k4;
#pragma unroll
    for (int q = 0; q < OUT; ++q) {
      acc[q] += xv[0] * Ws[(kb + 0) * OUT + q];
      acc[q] += xv[1] * Ws[(kb + 1) * OUT + q];
      acc[q] += xv[2] * Ws[(kb + 2) * OUT + q];
      acc[q] += xv[3] * Ws[(kb + 3) * OUT + q];
    }
  }
#pragma unroll
  for (int o = 1; o < SPLIT; o <<= 1) {
#pragma unroll
    for (int q = 0; q < OUT; ++q) acc[q] += __shfl_xor(acc[q], o);
  }
  constexpr int WCH = OUT / 4;
  if (j < WCH) {
    h4v v;
    v[0] = (_Float16)acc[4 * j + 0];
    v[1] = (_Float16)acc[4 * j + 1];
    v[2] = (_Float16)acc[4 * j + 2];
    v[3] = (_Float16)acc[4 * j + 3];
    reinterpret_cast<h4v*>(hout + (size_t)n * OUT)[j] = v;
  }
  if (j < H) {
    float ss = 0.f, dd = 0.f;
#pragma unroll
    for (int c = 0; c < C; ++c) {
      ss += acc[j * C + c] * As[j * C + c];
      dd += acc[j * C + c] * Ad[j * C + c];
    }
    as_[n * H + j] = ss;
    ad_[n * H + j] = dd;
  }
}

// ================= edge layer 1 + fused node transform 2 =================
// L=2 lanes x 16B h1 gathers, S=4, masked int4 chunks (R9-measured-best form).
// Epilogue writes packed Rec2 {h2, as2} + separate ad2.

__global__ void k_edge12(const int* __restrict__ rowStart, const int* __restrict__ colIdx,
                         const _Float16* __restrict__ h1, const float* __restrict__ as_,
                         const float* __restrict__ ad_, const float* __restrict__ b1,
                         const float* __restrict__ W2, const float* __restrict__ as2w,
                         const float* __restrict__ ad2w, Rec2* __restrict__ r2,
                         float* __restrict__ ad2, int N, int R8) {
  constexpr int L = 2, S = 4, LS = 8, NPB = TB / LS;
  __shared__ float Ws2[128], A2s[8], A2d[8], B1s[16];
  if (threadIdx.x < 128) Ws2[threadIdx.x] = W2[threadIdx.x];
  if (threadIdx.x < 8) {
    A2s[threadIdx.x] = as2w[threadIdx.x];
    A2d[threadIdx.x] = ad2w[threadIdx.x];
  }
  if (threadIdx.x < 16) B1s[threadIdx.x] = b1[threadIdx.x];
  __syncthreads();
  const int g = blockIdx.x & (NGRP - 1);
  const int lb = blockIdx.x / NGRP;
  const int lane = threadIdx.x % LS;
  const int sub = lane >> 1;
  const int j = lane & 1;
  const int n = g * R8 + lb * NPB + threadIdx.x / LS;
  const int nEnd = min((g + 1) * R8, N);
  if (n >= nEnd) return;
  const float adv = ad_[n * 2 + j];
  const int start = rowStart[n];
  const int end = rowStart[n + 1];
  float s = 0.f, acc[8];
#pragma unroll
  for (int q = 0; q < 8; ++q) acc[q] = 0.f;
  if (sub == 0) {  // self-loop
    float p = __expf(leaky(as_[n * 2 + j] + adv));
    h8v a0 = reinterpret_cast<const h8v*>(h1 + (size_t)n * 16)[j];
    s = p;
#pragma unroll
    for (int q = 0; q < 8; ++q) acc[q] = p * (float)a0[q];
  }
  const int base = start & ~3;
  const int nch = (end - base + 3) >> 2;
  for (int t = sub; t < nch; t += S) {
    const int i0 = base + 4 * t;
    i4v cv = *reinterpret_cast<const i4v*>(colIdx + i0);
#pragma unroll
    for (int k = 0; k < 4; ++k) {
      const bool ok = (i0 + k >= start) && (i0 + k < end);
      const int src = ok ? cv[k] : n;
      h8v hv = reinterpret_cast<const h8v*>(h1 + (size_t)src * 16)[j];
      float e = as_[src * 2 + j];
      float p = ok ? __expf(leaky(e + adv)) : 0.f;
      s += p;
#pragma unroll
      for (int q = 0; q < 8; ++q) acc[q] += p * (float)hv[q];
    }
  }
#pragma unroll
  for (int off = L; off < LS; off <<= 1) {
    s += __shfl_xor(s, off);
#pragma unroll
    for (int q = 0; q < 8; ++q) acc[q] += __shfl_xor(acc[q], off);
  }
  if (sub == 0) {
    float inv = 1.f / (s + 1e-16f);
    float o1v[8];
#pragma unroll
    for (int q = 0; q < 8; ++q) o1v[q] = fmaxf(acc[q] * inv + B1s[j * 8 + q], 0.f);
    float h2p[8];
#pragma unroll
    for (int q = 0; q < 8; ++q) {
      float tacc = 0.f;
#pragma unroll
      for (int c = 0; c < 8; ++c) tacc += o1v[c] * Ws2[(j * 8 + c) * 8 + q];
      h2p[q] = tacc;
    }
    float h2f[8];
#pragma unroll
    for (int q = 0; q < 8; ++q) h2f[q] = h2p[q] + __shfl_xor(h2p[q], 1);
    h4v v;
#pragma unroll
    for (int q = 0; q < 4; ++q) v[q] = (_Float16)h2f[j * 4 + q];
    reinterpret_cast<h4v*>(r2[n].h)[j] = v;
    float ss = 0.f, dd = 0.f;
#pragma unroll
    for (int c = 0; c < 4; ++c) {
      ss += h2f[j * 4 + c] * A2s[j * 4 + c];
      dd += h2f[j * 4 + c] * A2d[j * 4 + c];
    }
    r2[n].as[j] = ss;
    ad2[n * 2 + j] = dd;
  }
}

// ================= edge layer 2 + fused node transform 3 =================
// Packed Rec2 gathers: one 32B record = one line per edge.

__global__ void k_edge23(const int* __restrict__ rowStart, const int* __restrict__ colIdx,
                         const Rec2* __restrict__ r2, const float* __restrict__ ad_,
                         const float* __restrict__ b2, const float* __restrict__ W3,
                         const float* __restrict__ as3w, const float* __restrict__ ad3w,
                         Rec3* __restrict__ r3, float* __restrict__ ad3, int N, int R8) {
  constexpr int L = 2, S = 4, LS = 8, NPB = TB / LS;
  __shared__ float Ws3[32], A3s[4], A3d[4], B2s[8];
  if (threadIdx.x < 32) Ws3[threadIdx.x] = W3[threadIdx.x];
  if (threadIdx.x < 4) {
    A3s[threadIdx.x] = as3w[threadIdx.x];
    A3d[threadIdx.x] = ad3w[threadIdx.x];
  }
  if (threadIdx.x < 8) B2s[threadIdx.x] = b2[threadIdx.x];
  __syncthreads();
  const int g = blockIdx.x & (NGRP - 1);
  const int lb = blockIdx.x / NGRP;
  const int lane = threadIdx.x % LS;
  const int sub = lane >> 1;
  const int j = lane & 1;
  const int n = g * R8 + lb * NPB + threadIdx.x / LS;
  const int nEnd = min((g + 1) * R8, N);
  if (n >= nEnd) return;
  const float adv = ad_[n * 2 + j];
  const int start = rowStart[n];
  const int end = rowStart[n + 1];
  float s = 0.f, acc[4];
#pragma unroll
  for (int q = 0; q < 4; ++q) acc[q] = 0.f;
  if (sub == 0) {
    float p = __expf(leaky(r2[n].as[j] + adv));
    h4v a0 = reinterpret_cast<const h4v*>(r2[n].h)[j];
    s = p;
#pragma unroll
    for (int q = 0; q < 4; ++q) acc[q] = p * (float)a0[q];
  }
  const int base = start & ~3;
  const int nch = (end - base + 3) >> 2;
  for (int t = sub; t < nch; t += S) {
    const int i0 = base + 4 * t;
    i4v cv = *reinterpret_cast<const i4v*>(colIdx + i0);
#pragma unroll
    for (int k = 0; k < 4; ++k) {
      const bool ok = (i0 + k >= start) && (i0 + k < end);
      const int src = ok ? cv[k] : n;
      h4v hv = reinterpret_cast<const h4v*>(r2[src].h)[j];
      float e = r2[src].as[j];
      float p = ok ? __expf(leaky(e + adv)) : 0.f;
      s += p;
#pragma unroll
      for (int q = 0; q < 4; ++q) acc[q] += p * (float)hv[q];
    }
  }
#pragma unroll
  for (int off = L; off < LS; off <<= 1) {
    s += __shfl_xor(s, off);
#pragma unroll
    for (int q = 0; q < 4; ++q) acc[q] += __shfl_xor(acc[q], off);
  }
  if (sub == 0) {
    float inv = 1.f / (s + 1e-16f);
    float o2v[4];
#pragma unroll
    for (int q = 0; q < 4; ++q) o2v[q] = fmaxf(acc[q] * inv + B2s[j * 4 + q], 0.f);
    float h3p[4];
#pragma unroll
    for (int q = 0; q < 4; ++q) {
      float tacc = 0.f;
#pragma unroll
      for (int c = 0; c < 4; ++c) tacc += o2v[c] * Ws3[(j * 4 + c) * 4 + q];
      h3p[q] = tacc;
    }
    float h3f[4];
#pragma unroll
    for (int q = 0; q < 4; ++q) h3f[q] = h3p[q] + __shfl_xor(h3p[q], 1);
    if (j == 0) {
      Rec3 rec;
#pragma unroll
      for (int q = 0; q < 4; ++q) rec.h[q] = (_Float16)h3f[q];
      float ss = 0.f, dd = 0.f;
#pragma unroll
      for (int c = 0; c < 4; ++c) {
        ss += h3f[c] * A3s[c];
        dd += h3f[c] * A3d[c];
      }
      rec.as = ss;
      rec.pad = 0.f;
      r3[n] = rec;
      ad3[n] = dd;
    }
  }
}

// ================= edge layer 3 + fused classifier; S=8 =================
// Packed Rec3 gathers: ONE 16B load per edge fetches feature + logit.

__global__ void k_edge3(const int* __restrict__ rowStart, const int* __restrict__ colIdx,
                        const Rec3* __restrict__ r3, const float* __restrict__ ad_,
                        const float* __restrict__ b3, const float* __restrict__ Wc,
                        const float* __restrict__ bc, float* __restrict__ out,
                        int N, int R8) {
  constexpr int S = 8;
  constexpr int NPB = TB / S;
  const int g = blockIdx.x & (NGRP - 1);
  const int lb = blockIdx.x / NGRP;
  const int sub = threadIdx.x % S;
  const int n = g * R8 + lb * NPB + threadIdx.x / S;
  const int nEnd = min((g + 1) * R8, N);
  if (n >= nEnd) return;
  const float adv = ad_[n];
  const int start = rowStart[n];
  const int end = rowStart[n + 1];
  float s = 0.f, acc0 = 0.f, acc1 = 0.f, acc2 = 0.f, acc3 = 0.f;
  if (sub == 0) {
    Rec3 rec = r3[n];
    float p = __expf(leaky(rec.as + adv));
    s = p;
    acc0 = p * (float)rec.h[0];
    acc1 = p * (float)rec.h[1];
    acc2 = p * (float)rec.h[2];
    acc3 = p * (float)rec.h[3];
  }
  const int base = start & ~3;
  const int nch = (end - base + 3) >> 2;
  for (int t = sub; t < nch; t += S) {
    const int i0 = base + 4 * t;
    i4v cv = *reinterpret_cast<const i4v*>(colIdx + i0);
#pragma unroll
    for (int k = 0; k < 4; ++k) {
      const bool ok = (i0 + k >= start) && (i0 + k < end);
      const int src = ok ? cv[k] : n;
      Rec3 rec = r3[src];
      float p = ok ? __expf(leaky(rec.as + adv)) : 0.f;
      s += p;
      acc0 += p * (float)rec.h[0];
      acc1 += p * (float)rec.h[1];
      acc2 += p * (float)rec.h[2];
      acc3 += p * (float)rec.h[3];
    }
  }
#pragma unroll
  for (int off = 1; off < S; off <<= 1) {
    s += __shfl_xor(s, off);
    acc0 += __shfl_xor(acc0, off);
    acc1 += __shfl_xor(acc1, off);
    acc2 += __shfl_xor(acc2, off);
    acc3 += __shfl_xor(acc3, off);
  }
  if (sub == 0) {
    float inv = 1.f / (s + 1e-16f);
    float o0 = acc0 * inv + b3[0];
    float o1 = acc1 * inv + b3[1];
    float o2 = acc2 * inv + b3[2];
    float o3 = acc3 * inv + b3[3];
    float2 r;
    r.x = o0 * Wc[0] + o1 * Wc[2] + o2 * Wc[4] + o3 * Wc[6] + bc[0];
    r.y = o0 * Wc[1] + o1 * Wc[3] + o2 * Wc[5] + o3 * Wc[7] + bc[1];
    reinterpret_cast<float2*>(out)[n] = r;
  }
}

// ================= launch =================

extern "C" void kernel_launch(void* const* d_in, const int* in_sizes, int n_in,
                              void* d_out, int out_size, void* d_ws, size_t ws_size,
                              hipStream_t stream) {
  const float* x    = (const float*)d_in[0];
  const int*   ei   = (const int*)d_in[1];
  const float* W1   = (const float*)d_in[2];
  const float* as1w = (const float*)d_in[3];
  const float* ad1w = (const float*)d_in[4];
  const float* b1   = (const float*)d_in[5];
  const float* W2   = (const float*)d_in[6];
  const float* as2w = (const float*)d_in[7];
  const float* ad2w = (const float*)d_in[8];
  const float* b2   = (const float*)d_in[9];
  const float* W3   = (const float*)d_in[10];
  const float* as3w = (const float*)d_in[11];
  const float* ad3w = (const float*)d_in[12];
  const float* b3   = (const float*)d_in[13];
  const float* Wc   = (const float*)d_in[14];
  const float* bc   = (const float*)d_in[15];
  float* out = (float*)d_out;

  const int N = in_sizes[0] / 128;
  const int E = in_sizes[1] / 2;
  const int* srcA = ei;
  const int* dstA = ei + E;

  char* p = (char*)d_ws;
  auto alloc = [&](size_t bytes) -> void* {
    void* r = (void*)p;
    p += (bytes + 255) & ~(size_t)255;
    return r;
  };
  int* cnt        = (int*)alloc((size_t)NBKT * NB_P * 4);
  int* off        = (int*)alloc((size_t)NBKT * NB_P * 4);
  int* colTotal   = (int*)alloc(NBKT * 4);
  int* bucketBase = (int*)alloc((NBKT + 1) * 4);
  int* rowStart   = (int*)alloc((size_t)(N + 1) * 4);
  int* epk        = (int*)alloc((size_t)E * 4);
  int* colIdx     = (int*)alloc((size_t)E * 4 + 256);
  _Float16* h1 = (_Float16*)alloc((size_t)N * 16 * 2);
  float* as1 = (float*)alloc((size_t)N * 2 * 4);
  float* ad1 = (float*)alloc((size_t)N * 2 * 4);
  Rec2* r2   = (Rec2*)alloc((size_t)N * sizeof(Rec2));
  float* ad2 = (float*)alloc((size_t)N * 2 * 4);
  Rec3* r3   = (Rec3*)alloc((size_t)N * sizeof(Rec3));
  float* ad3 = (float*)alloc((size_t)N * 4);

  const int R   = (N + NBKT - 1) / NBKT;                       // nodes per bucket (391)
  const unsigned M = (unsigned)(((1ULL << 32) + R - 1) / R);   // exact /R via __umulhi
  const int R8  = R * (NBKT / NGRP);                           // nodes per XCD (12512)
  const int E4  = E >> 2;
  const int CH4 = (E4 + NB_P - 1) / NB_P;

  // CSR build (no global atomics; coalesced epk and colIdx writes)
  k_bcount<<<NB_P, TBP, 0, stream>>>(dstA, cnt, E4, E, M, CH4);
  k_bscan1<<<NBKT, NB_P, 0, stream>>>(cnt, off, colTotal);
  k_bscan2<<<1, NBKT, 0, stream>>>(colTotal, bucketBase);
  k_bscatter<<<NB_P, TBP, 0, stream>>>(srcA, dstA, cnt, off, bucketBase, epk, E4, E, M, R, CH4);
  k_bsort<<<NBKT, SORT_T, 0, stream>>>(epk, bucketBase, rowStart, colIdx, N, R, E);

  const int nb1 = (N + (TB / 4) - 1) / (TB / 4);
  const int ge8 = NGRP * ((R8 + (TB / 8) - 1) / (TB / 8));  // 32 nodes/block

  k_node<128, 2, 8, 4, true><<<nb1, TB, 0, stream>>>(x, W1, as1w, ad1w, h1, as1, ad1, N);
  k_edge12<<<ge8, TB, 0, stream>>>(rowStart, colIdx, h1, as1, ad1, b1, W2, as2w, ad2w,
                                   r2, ad2, N, R8);
  k_edge23<<<ge8, TB, 0, stream>>>(rowStart, colIdx, r2, ad2, b2, W3, as3w, ad3w,
                                   r3, ad3, N, R8);
  k_edge3<<<ge8, TB, 0, stream>>>(rowStart, colIdx, r3, ad3, b3, Wc, bc, out, N, R8);
}

// Round 13
// 172.178 us; speedup vs baseline: 1.1880x; 1.0332x over previous
//
#include <hip/hip_runtime.h>

#define TB 256
#define NGRP 8            // XCDs on MI355X
#define NB_P 512          // partition blocks
#define TBP 256           // partition block threads
#define NBKT 256          // dst-range buckets (32 per XCD)
#define SORT_T 1024
#define STG_CAP 14336     // LDS staging entries in k_bsort (56 KB)
#define STG2_CAP 6400     // LDS staging entries in k_bscatter (25.6 KB)

typedef int      i4v __attribute__((ext_vector_type(4)));
typedef float    f4v __attribute__((ext_vector_type(4)));
typedef _Float16 h4v __attribute__((ext_vector_type(4)));
typedef _Float16 h8v __attribute__((ext_vector_type(8)));

// Packed gather records: one cache line fetch per edge.
struct __align__(16) Rec2 { _Float16 h[8]; float as[2]; float pad[2]; };  // 32 B
struct __align__(16) Rec3 { _Float16 h[4]; float as; float pad; };        // 16 B

static __device__ __forceinline__ float leaky(float x) {
  return x > 0.f ? x : 0.2f * x;
}

// ========== fused A1 + node1: blocks [0,NB_P) bucket-count, rest do x@W1 ==========
// Independent work overlapped in one dispatch (node1's 51MB x-stream rides under
// bcount's LDS-atomic histogram).

__global__ void __launch_bounds__(TB)
k_bcount_node1(const int* __restrict__ dstA, int* __restrict__ cnt,
               int E4, int E, unsigned M, int CH4,
               const float* __restrict__ xin, const float* __restrict__ W1,
               const float* __restrict__ a_src, const float* __restrict__ a_dst,
               _Float16* __restrict__ hout, float* __restrict__ as_,
               float* __restrict__ ad_, int N) {
  __shared__ __align__(16) char smem[8448];
  if (blockIdx.x < NB_P) {
    // ---- bucket count: 4 sub-histograms (one per wave) ----
    int* lc = (int*)smem;
    for (int i = threadIdx.x; i < 4 * NBKT; i += TBP) lc[i] = 0;
    __syncthreads();
    int* lcw = lc + (threadIdx.x >> 6) * NBKT;
    const int bstart = blockIdx.x * CH4;
    const int bend = min(E4, bstart + CH4);
    const i4v* d4 = reinterpret_cast<const i4v*>(dstA);
    for (int i = bstart + threadIdx.x; i < bend; i += TBP) {
      i4v d = __builtin_nontemporal_load(&d4[i]);
#pragma unroll
      for (int k = 0; k < 4; ++k) atomicAdd(&lcw[__umulhi((unsigned)d[k], M)], 1);
    }
    if (blockIdx.x == NB_P - 1) {
      for (int t = E4 * 4 + threadIdx.x; t < E; t += TBP)
        atomicAdd(&lcw[__umulhi((unsigned)dstA[t], M)], 1);
    }
    __syncthreads();
    for (int b = threadIdx.x; b < NBKT; b += TBP)
      cnt[b * NB_P + blockIdx.x] = lc[b] + lc[NBKT + b] + lc[2 * NBKT + b] + lc[3 * NBKT + b];
  } else {
    // ---- node transform layer 1: IN=128, H=2, C=8, SPLIT=4 ----
    constexpr int IN = 128, OUT = 16, SPLIT = 4, NPB = TB / SPLIT, PIN4 = IN / SPLIT / 4;
    float* Ws = (float*)smem;            // 2048 floats
    float* As = (float*)(smem + 8192);   // 16
    float* Ad = (float*)(smem + 8256);   // 16
    const int bid = blockIdx.x - NB_P;
    for (int i = threadIdx.x; i < IN * OUT; i += TB) Ws[i] = W1[i];
    if (threadIdx.x < OUT) {
      As[threadIdx.x] = a_src[threadIdx.x];
      Ad[threadIdx.x] = a_dst[threadIdx.x];
    }
    __syncthreads();
    const int j = threadIdx.x & (SPLIT - 1);
    const int n = bid * NPB + threadIdx.x / SPLIT;
    if (n >= N) return;
    float acc[OUT];
#pragma unroll
    for (int q = 0; q < OUT; ++q) acc[q] = 0.f;
    const f4v* x4 = reinterpret_cast<const f4v*>(xin + (size_t)n * IN + j * (IN / SPLIT));
#pragma unroll
    for (int k4 = 0; k4 < PIN4; ++k4) {
      f4v xv = __builtin_nontemporal_load(&x4[k4]);
      const int kb = j * (IN / SPLIT) + 4 * k4;
#pragma unroll
      for (int q = 0; q < OUT; ++q) {
        acc[q] += xv[0] * Ws[(kb + 0) * OUT + q];
        acc[q] += xv[1] * Ws[(kb + 1) * OUT + q];
        acc[q] += xv[2] * Ws[(kb + 2) * OUT + q];
        acc[q] += xv[3] * Ws[(kb + 3) * OUT + q];
      }
    }
#pragma unroll
    for (int o = 1; o < SPLIT; o <<= 1) {
#pragma unroll
      for (int q = 0; q < OUT; ++q) acc[q] += __shfl_xor(acc[q], o);
    }
    if (j < OUT / 4) {
      h4v v;
      v[0] = (_Float16)acc[4 * j + 0];
      v[1] = (_Float16)acc[4 * j + 1];
      v[2] = (_Float16)acc[4 * j + 2];
      v[3] = (_Float16)acc[4 * j + 3];
      reinterpret_cast<h4v*>(hout + (size_t)n * OUT)[j] = v;
    }
    if (j < 2) {
      float ss = 0.f, dd = 0.f;
#pragma unroll
      for (int c = 0; c < 8; ++c) {
        ss += acc[j * 8 + c] * As[j * 8 + c];
        dd += acc[j * 8 + c] * Ad[j * 8 + c];
      }
      as_[n * 2 + j] = ss;
      ad_[n * 2 + j] = dd;
    }
  }
}

// A2a: per-bucket exclusive scan over blocks (grid = NBKT, block = NB_P threads).
__global__ void k_bscan1(const int* __restrict__ cnt, int* __restrict__ off,
                         int* __restrict__ colTotal) {
  __shared__ int sh[NB_P];
  const int t = threadIdx.x;
  const int b = blockIdx.x;
  int v = cnt[b * NB_P + t];
  sh[t] = v;
  __syncthreads();
  for (int o = 1; o < NB_P; o <<= 1) {
    int u = (t >= o) ? sh[t - o] : 0;
    __syncthreads();
    sh[t] += u;
    __syncthreads();
  }
  off[b * NB_P + t] = sh[t] - v;
  if (t == NB_P - 1) colTotal[b] = sh[t];
}

// A2b: exclusive scan of bucket totals -> bucketBase[NBKT+1].
__global__ void k_bscan2(const int* __restrict__ colTotal, int* __restrict__ bucketBase) {
  __shared__ int sh[NBKT];
  const int t = threadIdx.x;
  int v = colTotal[t];
  sh[t] = v;
  __syncthreads();
  for (int o = 1; o < NBKT; o <<= 1) {
    int u = (t >= o) ? sh[t - o] : 0;
    __syncthreads();
    sh[t] += u;
    __syncthreads();
  }
  bucketBase[t] = sh[t] - v;
  if (t == NBKT - 1) bucketBase[NBKT] = sh[t];
}

// A3: LDS-staged scatter; coalesced flush to global bucket segments.
__global__ void k_bscatter(const int* __restrict__ srcA, const int* __restrict__ dstA,
                           const int* __restrict__ cnt, const int* __restrict__ off,
                           const int* __restrict__ bucketBase, int* __restrict__ epk,
                           int E4, int E, unsigned M, int R, int CH4) {
  __shared__ int loff[NBKT + 1];
  __shared__ int lcur[NBKT];
  __shared__ int gbase[NBKT];
  __shared__ int stg[STG2_CAP];
  const int t = threadIdx.x;
  {
    int v = cnt[t * NB_P + blockIdx.x];
    loff[t] = v;
    __syncthreads();
    for (int o = 1; o < NBKT; o <<= 1) {
      int u = (t >= o) ? loff[t - o] : 0;
      __syncthreads();
      loff[t] += u;
      __syncthreads();
    }
    int incl = loff[t];
    __syncthreads();
    loff[t] = incl - v;
    lcur[t] = incl - v;
    if (t == NBKT - 1) loff[NBKT] = incl;
    gbase[t] = bucketBase[t] + off[t * NB_P + blockIdx.x];
  }
  __syncthreads();
  const int bstart = blockIdx.x * CH4;
  const int bend = min(E4, bstart + CH4);
  const i4v* d4 = reinterpret_cast<const i4v*>(dstA);
  const i4v* s4 = reinterpret_cast<const i4v*>(srcA);
  for (int i = bstart + t; i < bend; i += TBP) {
    i4v d = __builtin_nontemporal_load(&d4[i]);
    i4v sv = __builtin_nontemporal_load(&s4[i]);
#pragma unroll
    for (int k = 0; k < 4; ++k) {
      int dd = d[k];
      int b = __umulhi((unsigned)dd, M);
      int pos = atomicAdd(&lcur[b], 1);
      stg[pos] = ((dd - b * R) << 17) | sv[k];
    }
  }
  if (blockIdx.x == NB_P - 1) {
    for (int i = E4 * 4 + t; i < E; i += TBP) {
      int dd = dstA[i];
      int b = __umulhi((unsigned)dd, M);
      int pos = atomicAdd(&lcur[b], 1);
      stg[pos] = ((dd - b * R) << 17) | srcA[i];
    }
  }
  __syncthreads();
  const int total = loff[NBKT];
  for (int i = t; i < total; i += TBP) {
    int loQ = 0, hiQ = NBKT;
#pragma unroll
    for (int it = 0; it < 8; ++it) {
      int mid = (loQ + hiQ) >> 1;
      if (loff[mid] <= i) loQ = mid; else hiQ = mid;
    }
    epk[gbase[loQ] + (i - loff[loQ])] = stg[i];
  }
}

// B: per-bucket counting sort; LDS staging, coalesced colIdx write.
__global__ void k_bsort(const int* __restrict__ epk, const int* __restrict__ bucketBase,
                        int* __restrict__ rowStart, int* __restrict__ colIdx,
                        int N, int R, int E) {
  __shared__ int sc[512];
  __shared__ int stg[STG_CAP];
  const int b = (blockIdx.x & (NGRP - 1)) * (NBKT / NGRP) + (blockIdx.x >> 3);
  const int lo = bucketBase[b], hi = bucketBase[b + 1];
  const int cnt = hi - lo;
  const int nodeLo = b * R;
  const int nN = min(R, N - nodeLo);
  const int t = threadIdx.x;
  if (t < 512) sc[t] = 0;
  __syncthreads();
  for (int i = lo + t; i < hi; i += SORT_T) {
    int pk = __builtin_nontemporal_load(&epk[i]);
    atomicAdd(&sc[pk >> 17], 1);
  }
  __syncthreads();
  int own = (t < 512) ? sc[t] : 0;
  for (int o = 1; o < 512; o <<= 1) {
    int u = (t < 512 && t >= o) ? sc[t - o] : 0;
    __syncthreads();
    if (t < 512) sc[t] += u;
    __syncthreads();
  }
  if (t < nN) rowStart[nodeLo + t] = lo + sc[t] - own;
  if (b == NBKT - 1 && t == 0) rowStart[N] = E;
  if (t < 512) sc[t] -= own;
  __syncthreads();
  if (cnt <= STG_CAP) {
    for (int i = lo + t; i < hi; i += SORT_T) {
      int pk = epk[i];
      int pos = atomicAdd(&sc[pk >> 17], 1);
      stg[pos] = pk & 0x1FFFF;
    }
    __syncthreads();
    for (int i = t; i < cnt; i += SORT_T) colIdx[lo + i] = stg[i];  // coalesced
  } else {
    for (int i = lo + t; i < hi; i += SORT_T) {
      int pk = epk[i];
      int pos = lo + atomicAdd(&sc[pk >> 17], 1);
      colIdx[pos] = pk & 0x1FFFF;
    }
  }
}

// ================= edge layer 1 + fused node transform 2 =================
// L=2 x 16B h1 gathers, S=4, masked chunks; colIdx software-pipelined.

__global__ void k_edge12(const int* __restrict__ rowStart, const int* __restrict__ colIdx,
                         const _Float16* __restrict__ h1, const float* __restrict__ as_,
                         const float* __restrict__ ad_, const float* __restrict__ b1,
                         const float* __restrict__ W2, const float* __restrict__ as2w,
                         const float* __restrict__ ad2w, Rec2* __restrict__ r2,
                         float* __restrict__ ad2, int N, int R8) {
  constexpr int L = 2, S = 4, LS = 8, NPB = TB / LS;
  __shared__ float Ws2[128], A2s[8], A2d[8], B1s[16];
  if (threadIdx.x < 128) Ws2[threadIdx.x] = W2[threadIdx.x];
  if (threadIdx.x < 8) {
    A2s[threadIdx.x] = as2w[threadIdx.x];
    A2d[threadIdx.x] = ad2w[threadIdx.x];
  }
  if (threadIdx.x < 16) B1s[threadIdx.x] = b1[threadIdx.x];
  __syncthreads();
  const int g = blockIdx.x & (NGRP - 1);
  const int lb = blockIdx.x / NGRP;
  const int lane = threadIdx.x % LS;
  const int sub = lane >> 1;
  const int j = lane & 1;
  const int n = g * R8 + lb * NPB + threadIdx.x / LS;
  const int nEnd = min((g + 1) * R8, N);
  if (n >= nEnd) return;
  const float adv = ad_[n * 2 + j];
  const int start = rowStart[n];
  const int end = rowStart[n + 1];
  float s = 0.f, acc[8];
#pragma unroll
  for (int q = 0; q < 8; ++q) acc[q] = 0.f;
  if (sub == 0) {  // self-loop
    float p = __expf(leaky(as_[n * 2 + j] + adv));
    h8v a0 = reinterpret_cast<const h8v*>(h1 + (size_t)n * 16)[j];
    s = p;
#pragma unroll
    for (int q = 0; q < 8; ++q) acc[q] = p * (float)a0[q];
  }
  const int base = start & ~3;
  const int nch = (end - base + 3) >> 2;
  i4v cv;
  if (sub < nch) cv = *reinterpret_cast<const i4v*>(colIdx + base + 4 * sub);
  for (int t = sub; t < nch; t += S) {
    i4v nxt = cv;
    if (t + S < nch) nxt = *reinterpret_cast<const i4v*>(colIdx + base + 4 * (t + S));
    const int i0 = base + 4 * t;
#pragma unroll
    for (int k = 0; k < 4; ++k) {
      const bool ok = (i0 + k >= start) && (i0 + k < end);
      const int src = ok ? cv[k] : n;
      h8v hv = reinterpret_cast<const h8v*>(h1 + (size_t)src * 16)[j];
      float e = as_[src * 2 + j];
      float p = ok ? __expf(leaky(e + adv)) : 0.f;
      s += p;
#pragma unroll
      for (int q = 0; q < 8; ++q) acc[q] += p * (float)hv[q];
    }
    cv = nxt;
  }
#pragma unroll
  for (int off = L; off < LS; off <<= 1) {
    s += __shfl_xor(s, off);
#pragma unroll
    for (int q = 0; q < 8; ++q) acc[q] += __shfl_xor(acc[q], off);
  }
  if (sub == 0) {
    float inv = 1.f / (s + 1e-16f);
    float o1v[8];
#pragma unroll
    for (int q = 0; q < 8; ++q) o1v[q] = fmaxf(acc[q] * inv + B1s[j * 8 + q], 0.f);
    float h2p[8];
#pragma unroll
    for (int q = 0; q < 8; ++q) {
      float tacc = 0.f;
#pragma unroll
      for (int c = 0; c < 8; ++c) tacc += o1v[c] * Ws2[(j * 8 + c) * 8 + q];
      h2p[q] = tacc;
    }
    float h2f[8];
#pragma unroll
    for (int q = 0; q < 8; ++q) h2f[q] = h2p[q] + __shfl_xor(h2p[q], 1);
    h4v v;
#pragma unroll
    for (int q = 0; q < 4; ++q) v[q] = (_Float16)h2f[j * 4 + q];
    reinterpret_cast<h4v*>(r2[n].h)[j] = v;
    float ss = 0.f, dd = 0.f;
#pragma unroll
    for (int c = 0; c < 4; ++c) {
      ss += h2f[j * 4 + c] * A2s[j * 4 + c];
      dd += h2f[j * 4 + c] * A2d[j * 4 + c];
    }
    r2[n].as[j] = ss;
    ad2[n * 2 + j] = dd;
  }
}

// ================= edge layer 2 + fused node transform 3 =================

__global__ void k_edge23(const int* __restrict__ rowStart, const int* __restrict__ colIdx,
                         const Rec2* __restrict__ r2, const float* __restrict__ ad_,
                         const float* __restrict__ b2, const float* __restrict__ W3,
                         const float* __restrict__ as3w, const float* __restrict__ ad3w,
                         Rec3* __restrict__ r3, float* __restrict__ ad3, int N, int R8) {
  constexpr int L = 2, S = 4, LS = 8, NPB = TB / LS;
  __shared__ float Ws3[32], A3s[4], A3d[4], B2s[8];
  if (threadIdx.x < 32) Ws3[threadIdx.x] = W3[threadIdx.x];
  if (threadIdx.x < 4) {
    A3s[threadIdx.x] = as3w[threadIdx.x];
    A3d[threadIdx.x] = ad3w[threadIdx.x];
  }
  if (threadIdx.x < 8) B2s[threadIdx.x] = b2[threadIdx.x];
  __syncthreads();
  const int g = blockIdx.x & (NGRP - 1);
  const int lb = blockIdx.x / NGRP;
  const int lane = threadIdx.x % LS;
  const int sub = lane >> 1;
  const int j = lane & 1;
  const int n = g * R8 + lb * NPB + threadIdx.x / LS;
  const int nEnd = min((g + 1) * R8, N);
  if (n >= nEnd) return;
  const float adv = ad_[n * 2 + j];
  const int start = rowStart[n];
  const int end = rowStart[n + 1];
  float s = 0.f, acc[4];
#pragma unroll
  for (int q = 0; q < 4; ++q) acc[q] = 0.f;
  if (sub == 0) {
    float p = __expf(leaky(r2[n].as[j] + adv));
    h4v a0 = reinterpret_cast<const h4v*>(r2[n].h)[j];
    s = p;
#pragma unroll
    for (int q = 0; q < 4; ++q) acc[q] = p * (float)a0[q];
  }
  const int base = start & ~3;
  const int nch = (end - base + 3) >> 2;
  i4v cv;
  if (sub < nch) cv = *reinterpret_cast<const i4v*>(colIdx + base + 4 * sub);
  for (int t = sub; t < nch; t += S) {
    i4v nxt = cv;
    if (t + S < nch) nxt = *reinterpret_cast<const i4v*>(colIdx + base + 4 * (t + S));
    const int i0 = base + 4 * t;
#pragma unroll
    for (int k = 0; k < 4; ++k) {
      const bool ok = (i0 + k >= start) && (i0 + k < end);
      const int src = ok ? cv[k] : n;
      h4v hv = reinterpret_cast<const h4v*>(r2[src].h)[j];
      float e = r2[src].as[j];
      float p = ok ? __expf(leaky(e + adv)) : 0.f;
      s += p;
#pragma unroll
      for (int q = 0; q < 4; ++q) acc[q] += p * (float)hv[q];
    }
    cv = nxt;
  }
#pragma unroll
  for (int off = L; off < LS; off <<= 1) {
    s += __shfl_xor(s, off);
#pragma unroll
    for (int q = 0; q < 4; ++q) acc[q] += __shfl_xor(acc[q], off);
  }
  if (sub == 0) {
    float inv = 1.f / (s + 1e-16f);
    float o2v[4];
#pragma unroll
    for (int q = 0; q < 4; ++q) o2v[q] = fmaxf(acc[q] * inv + B2s[j * 4 + q], 0.f);
    float h3p[4];
#pragma unroll
    for (int q = 0; q < 4; ++q) {
      float tacc = 0.f;
#pragma unroll
      for (int c = 0; c < 4; ++c) tacc += o2v[c] * Ws3[(j * 4 + c) * 4 + q];
      h3p[q] = tacc;
    }
    float h3f[4];
#pragma unroll
    for (int q = 0; q < 4; ++q) h3f[q] = h3p[q] + __shfl_xor(h3p[q], 1);
    if (j == 0) {
      Rec3 rec;
#pragma unroll
      for (int q = 0; q < 4; ++q) rec.h[q] = (_Float16)h3f[q];
      float ss = 0.f, dd = 0.f;
#pragma unroll
      for (int c = 0; c < 4; ++c) {
        ss += h3f[c] * A3s[c];
        dd += h3f[c] * A3d[c];
      }
      rec.as = ss;
      rec.pad = 0.f;
      r3[n] = rec;
      ad3[n] = dd;
    }
  }
}

// ================= edge layer 3 + fused classifier; S=8 =================

__global__ void k_edge3(const int* __restrict__ rowStart, const int* __restrict__ colIdx,
                        const Rec3* __restrict__ r3, const float* __restrict__ ad_,
                        const float* __restrict__ b3, const float* __restrict__ Wc,
                        const float* __restrict__ bc, float* __restrict__ out,
                        int N, int R8) {
  constexpr int S = 8;
  constexpr int NPB = TB / S;
  const int g = blockIdx.x & (NGRP - 1);
  const int lb = blockIdx.x / NGRP;
  const int sub = threadIdx.x % S;
  const int n = g * R8 + lb * NPB + threadIdx.x / S;
  const int nEnd = min((g + 1) * R8, N);
  if (n >= nEnd) return;
  const float adv = ad_[n];
  const int start = rowStart[n];
  const int end = rowStart[n + 1];
  float s = 0.f, acc0 = 0.f, acc1 = 0.f, acc2 = 0.f, acc3 = 0.f;
  if (sub == 0) {
    Rec3 rec = r3[n];
    float p = __expf(leaky(rec.as + adv));
    s = p;
    acc0 = p * (float)rec.h[0];
    acc1 = p * (float)rec.h[1];
    acc2 = p * (float)rec.h[2];
    acc3 = p * (float)rec.h[3];
  }
  const int base = start & ~3;
  const int nch = (end - base + 3) >> 2;
  i4v cv;
  if (sub < nch) cv = *reinterpret_cast<const i4v*>(colIdx + base + 4 * sub);
  for (int t = sub; t < nch; t += S) {
    i4v nxt = cv;
    if (t + S < nch) nxt = *reinterpret_cast<const i4v*>(colIdx + base + 4 * (t + S));
    const int i0 = base + 4 * t;
#pragma unroll
    for (int k = 0; k < 4; ++k) {
      const bool ok = (i0 + k >= start) && (i0 + k < end);
      const int src = ok ? cv[k] : n;
      Rec3 rec = r3[src];
      float p = ok ? __expf(leaky(rec.as + adv)) : 0.f;
      s += p;
      acc0 += p * (float)rec.h[0];
      acc1 += p * (float)rec.h[1];
      acc2 += p * (float)rec.h[2];
      acc3 += p * (float)rec.h[3];
    }
    cv = nxt;
  }
#pragma unroll
  for (int off = 1; off < S; off <<= 1) {
    s += __shfl_xor(s, off);
    acc0 += __shfl_xor(acc0, off);
    acc1 += __shfl_xor(acc1, off);
    acc2 += __shfl_xor(acc2, off);
    acc3 += __shfl_xor(acc3, off);
  }
  if (sub == 0) {
    float inv = 1.f / (s + 1e-16f);
    float o0 = acc0 * inv + b3[0];
    float o1 = acc1 * inv + b3[1];
    float o2 = acc2 * inv + b3[2];
    float o3 = acc3 * inv + b3[3];
    float2 r;
    r.x = o0 * Wc[0] + o1 * Wc[2] + o2 * Wc[4] + o3 * Wc[6] + bc[0];
    r.y = o0 * Wc[1] + o1 * Wc[3] + o2 * Wc[5] + o3 * Wc[7] + bc[1];
    reinterpret_cast<float2*>(out)[n] = r;
  }
}

// ================= launch =================

extern "C" void kernel_launch(void* const* d_in, const int* in_sizes, int n_in,
                              void* d_out, int out_size, void* d_ws, size_t ws_size,
                              hipStream_t stream) {
  const float* x    = (const float*)d_in[0];
  const int*   ei   = (const int*)d_in[1];
  const float* W1   = (const float*)d_in[2];
  const float* as1w = (const float*)d_in[3];
  const float* ad1w = (const float*)d_in[4];
  const float* b1   = (const float*)d_in[5];
  const float* W2   = (const float*)d_in[6];
  const float* as2w = (const float*)d_in[7];
  const float* ad2w = (const float*)d_in[8];
  const float* b2   = (const float*)d_in[9];
  const float* W3   = (const float*)d_in[10];
  const float* as3w = (const float*)d_in[11];
  const float* ad3w = (const float*)d_in[12];
  const float* b3   = (const float*)d_in[13];
  const float* Wc   = (const float*)d_in[14];
  const float* bc   = (const float*)d_in[15];
  float* out = (float*)d_out;

  const int N = in_sizes[0] / 128;
  const int E = in_sizes[1] / 2;
  const int* srcA = ei;
  const int* dstA = ei + E;

  char* p = (char*)d_ws;
  auto alloc = [&](size_t bytes) -> void* {
    void* r = (void*)p;
    p += (bytes + 255) & ~(size_t)255;
    return r;
  };
  int* cnt        = (int*)alloc((size_t)NBKT * NB_P * 4);
  int* off        = (int*)alloc((size_t)NBKT * NB_P * 4);
  int* colTotal   = (int*)alloc(NBKT * 4);
  int* bucketBase = (int*)alloc((NBKT + 1) * 4);
  int* rowStart   = (int*)alloc((size_t)(N + 1) * 4);
  int* epk        = (int*)alloc((size_t)E * 4);
  int* colIdx     = (int*)alloc((size_t)E * 4 + 256);
  _Float16* h1 = (_Float16*)alloc((size_t)N * 16 * 2);
  float* as1 = (float*)alloc((size_t)N * 2 * 4);
  float* ad1 = (float*)alloc((size_t)N * 2 * 4);
  Rec2* r2   = (Rec2*)alloc((size_t)N * sizeof(Rec2));
  float* ad2 = (float*)alloc((size_t)N * 2 * 4);
  Rec3* r3   = (Rec3*)alloc((size_t)N * sizeof(Rec3));
  float* ad3 = (float*)alloc((size_t)N * 4);

  const int R   = (N + NBKT - 1) / NBKT;                       // nodes per bucket (391)
  const unsigned M = (unsigned)(((1ULL << 32) + R - 1) / R);   // exact /R via __umulhi
  const int R8  = R * (NBKT / NGRP);                           // nodes per XCD (12512)
  const int E4  = E >> 2;
  const int CH4 = (E4 + NB_P - 1) / NB_P;

  const int nb1 = (N + (TB / 4) - 1) / (TB / 4);   // node1 blocks (SPLIT=4)
  const int ge8 = NGRP * ((R8 + (TB / 8) - 1) / (TB / 8));  // 32 nodes/block

  // CSR build + node1 overlapped in the first dispatch
  k_bcount_node1<<<NB_P + nb1, TB, 0, stream>>>(dstA, cnt, E4, E, M, CH4,
                                                x, W1, as1w, ad1w, h1, as1, ad1, N);
  k_bscan1<<<NBKT, NB_P, 0, stream>>>(cnt, off, colTotal);
  k_bscan2<<<1, NBKT, 0, stream>>>(colTotal, bucketBase);
  k_bscatter<<<NB_P, TBP, 0, stream>>>(srcA, dstA, cnt, off, bucketBase, epk, E4, E, M, R, CH4);
  k_bsort<<<NBKT, SORT_T, 0, stream>>>(epk, bucketBase, rowStart, colIdx, N, R, E);

  k_edge12<<<ge8, TB, 0, stream>>>(rowStart, colIdx, h1, as1, ad1, b1, W2, as2w, ad2w,
                                   r2, ad2, N, R8);
  k_edge23<<<ge8, TB, 0, stream>>>(rowStart, colIdx, r2, ad2, b2, W3, as3w, ad3w,
                                   r3, ad3, N, R8);
  k_edge3<<<ge8, TB, 0, stream>>>(rowStart, colIdx, r3, ad3, b3, Wc, bc, out, N, R8);
}

// Round 14
// 168.813 us; speedup vs baseline: 1.2117x; 1.0199x over previous
//
#include <hip/hip_runtime.h>

#define TB 256
#define NGRP 8            // XCDs on MI355X
#define NB_P 512          // partition blocks
#define TBP 256           // partition block threads
#define NBKT 256          // dst-range buckets (32 per XCD)
#define SORT_T 1024
#define STG_CAP 14336     // LDS staging entries in k_bsort (56 KB)
#define STG2_CAP 6656     // LDS staging entries in k_scatter (26.6 KB)

typedef int      i4v __attribute__((ext_vector_type(4)));
typedef float    f4v __attribute__((ext_vector_type(4)));
typedef _Float16 h4v __attribute__((ext_vector_type(4)));
typedef _Float16 h8v __attribute__((ext_vector_type(8)));

// Packed gather records: one cache line fetch per edge.
struct __align__(16) Rec2 { _Float16 h[8]; float as[2]; float pad[2]; };  // 32 B
struct __align__(16) Rec3 { _Float16 h[4]; float as; float pad; };        // 16 B

static __device__ __forceinline__ float leaky(float x) {
  return x > 0.f ? x : 0.2f * x;
}

// ========== fused single-pass scatter + node1 ==========
// Blocks [0,NB_P): read own edge chunk ONCE, LDS counting-sort by bucket,
// linear coalesced flush to block-private epkPriv region; emit cnt + local
// offsets. Blocks [NB_P,...): layer-1 node transform x@W1.

__global__ void __launch_bounds__(TB)
k_scatter_node1(const int* __restrict__ srcA, const int* __restrict__ dstA,
                int* __restrict__ cnt, int* __restrict__ loffG,
                int* __restrict__ epkPriv, int E4, int E, unsigned M, int R,
                int CH4, int CHP,
                const float* __restrict__ xin, const float* __restrict__ W1,
                const float* __restrict__ a_src, const float* __restrict__ a_dst,
                _Float16* __restrict__ hout, float* __restrict__ as_,
                float* __restrict__ ad_, int N) {
  __shared__ __align__(16) char smem[33552];
  const int t = threadIdx.x;
  if (blockIdx.x < NB_P) {
    const int kblk = blockIdx.x;
    int* lc   = (int*)smem;                 // 4*NBKT sub-histograms (4 KB)
    int* loff = (int*)(smem + 4096);        // NBKT+1
    int* lcur = (int*)(smem + 5136);        // NBKT
    int* stg  = (int*)(smem + 6160);        // STG2_CAP
    for (int i = t; i < 4 * NBKT; i += TBP) lc[i] = 0;
    __syncthreads();
    int* lcw = lc + (t >> 6) * NBKT;
    const int bstart = kblk * CH4;
    const int bend = min(E4, bstart + CH4);
    const i4v* d4 = reinterpret_cast<const i4v*>(dstA);
    const i4v* s4 = reinterpret_cast<const i4v*>(srcA);
    // pass 1: histogram (cached dst loads -> L2-hot for pass 2)
    for (int i = bstart + t; i < bend; i += TBP) {
      i4v d = d4[i];
#pragma unroll
      for (int k = 0; k < 4; ++k) atomicAdd(&lcw[__umulhi((unsigned)d[k], M)], 1);
    }
    if (kblk == NB_P - 1) {
      for (int i = E4 * 4 + t; i < E; i += TBP)
        atomicAdd(&lcw[__umulhi((unsigned)dstA[i], M)], 1);
    }
    __syncthreads();
    // reduce sub-hists + exclusive scan -> local layout; emit cnt, loffG
    int c = 0;
    if (t < NBKT) {
      c = lc[t] + lc[NBKT + t] + lc[2 * NBKT + t] + lc[3 * NBKT + t];
      loff[t] = c;
    }
    __syncthreads();
    for (int o = 1; o < NBKT; o <<= 1) {
      int u = (t < NBKT && t >= o) ? loff[t - o] : 0;
      __syncthreads();
      if (t < NBKT) loff[t] += u;
      __syncthreads();
    }
    if (t < NBKT) {
      int excl = loff[t] - c;
      cnt[t * NB_P + kblk] = c;          // [bucket][block] for bscan1
      loffG[kblk * NBKT + t] = excl;     // block-major local offsets
      lcur[t] = excl;
      loff[t] = excl;
      if (t == NBKT - 1) loff[NBKT] = excl + c;
    }
    __syncthreads();
    // pass 2: scatter packed edges into LDS by bucket
    for (int i = bstart + t; i < bend; i += TBP) {
      i4v d = d4[i];
      i4v sv = __builtin_nontemporal_load(&s4[i]);
#pragma unroll
      for (int k = 0; k < 4; ++k) {
        int dd = d[k];
        int b = __umulhi((unsigned)dd, M);
        int pos = atomicAdd(&lcur[b], 1);
        stg[pos] = ((dd - b * R) << 17) | sv[k];
      }
    }
    if (kblk == NB_P - 1) {
      for (int i = E4 * 4 + t; i < E; i += TBP) {
        int dd = dstA[i];
        int b = __umulhi((unsigned)dd, M);
        int pos = atomicAdd(&lcur[b], 1);
        stg[pos] = ((dd - b * R) << 17) | srcA[i];
      }
    }
    __syncthreads();
    // linear coalesced flush to private region
    const int total = loff[NBKT];
    int* dst = epkPriv + (size_t)kblk * CHP;
    for (int i = t; i < total; i += TBP) dst[i] = stg[i];
  } else {
    // ---- node transform layer 1: IN=128, H=2, C=8, SPLIT=4 ----
    constexpr int IN = 128, OUT = 16, SPLIT = 4, NPB = TB / SPLIT, PIN4 = IN / SPLIT / 4;
    float* Ws = (float*)smem;
    float* As = (float*)(smem + 8192);
    float* Ad = (float*)(smem + 8256);
    const int bid = blockIdx.x - NB_P;
    for (int i = t; i < IN * OUT; i += TB) Ws[i] = W1[i];
    if (t < OUT) {
      As[t] = a_src[t];
      Ad[t] = a_dst[t];
    }
    __syncthreads();
    const int j = t & (SPLIT - 1);
    const int n = bid * NPB + t / SPLIT;
    if (n >= N) return;
    float acc[OUT];
#pragma unroll
    for (int q = 0; q < OUT; ++q) acc[q] = 0.f;
    const f4v* x4 = reinterpret_cast<const f4v*>(xin + (size_t)n * IN + j * (IN / SPLIT));
#pragma unroll
    for (int k4 = 0; k4 < PIN4; ++k4) {
      f4v xv = __builtin_nontemporal_load(&x4[k4]);
      const int kb = j * (IN / SPLIT) + 4 * k4;
#pragma unroll
      for (int q = 0; q < OUT; ++q) {
        acc[q] += xv[0] * Ws[(kb + 0) * OUT + q];
        acc[q] += xv[1] * Ws[(kb + 1) * OUT + q];
        acc[q] += xv[2] * Ws[(kb + 2) * OUT + q];
        acc[q] += xv[3] * Ws[(kb + 3) * OUT + q];
      }
    }
#pragma unroll
    for (int o = 1; o < SPLIT; o <<= 1) {
#pragma unroll
      for (int q = 0; q < OUT; ++q) acc[q] += __shfl_xor(acc[q], o);
    }
    if (j < OUT / 4) {
      h4v v;
      v[0] = (_Float16)acc[4 * j + 0];
      v[1] = (_Float16)acc[4 * j + 1];
      v[2] = (_Float16)acc[4 * j + 2];
      v[3] = (_Float16)acc[4 * j + 3];
      reinterpret_cast<h4v*>(hout + (size_t)n * OUT)[j] = v;
    }
    if (j < 2) {
      float ss = 0.f, dd = 0.f;
#pragma unroll
      for (int c = 0; c < 8; ++c) {
        ss += acc[j * 8 + c] * As[j * 8 + c];
        dd += acc[j * 8 + c] * Ad[j * 8 + c];
      }
      as_[n * 2 + j] = ss;
      ad_[n * 2 + j] = dd;
    }
  }
}

// A2a: per-bucket exclusive scan over blocks (grid = NBKT, block = NB_P threads).
__global__ void k_bscan1(const int* __restrict__ cnt, int* __restrict__ off,
                         int* __restrict__ colTotal) {
  __shared__ int sh[NB_P];
  const int t = threadIdx.x;
  const int b = blockIdx.x;
  int v = cnt[b * NB_P + t];
  sh[t] = v;
  __syncthreads();
  for (int o = 1; o < NB_P; o <<= 1) {
    int u = (t >= o) ? sh[t - o] : 0;
    __syncthreads();
    sh[t] += u;
    __syncthreads();
  }
  off[b * NB_P + t] = sh[t] - v;
  if (t == NB_P - 1) colTotal[b] = sh[t];
}

// A2b: exclusive scan of bucket totals -> bucketBase[NBKT+1].
__global__ void k_bscan2(const int* __restrict__ colTotal, int* __restrict__ bucketBase) {
  __shared__ int sh[NBKT];
  const int t = threadIdx.x;
  int v = colTotal[t];
  sh[t] = v;
  __syncthreads();
  for (int o = 1; o < NBKT; o <<= 1) {
    int u = (t >= o) ? sh[t - o] : 0;
    __syncthreads();
    sh[t] += u;
    __syncthreads();
  }
  bucketBase[t] = sh[t] - v;
  if (t == NBKT - 1) bucketBase[NBKT] = sh[t];
}

// B: per-bucket counting sort. Edges gathered from block-private runs via
// binary search over off-row; LDS staging; coalesced colIdx write.
__global__ void k_bsort(const int* __restrict__ epkPriv, const int* __restrict__ off,
                        const int* __restrict__ loffG, const int* __restrict__ bucketBase,
                        int* __restrict__ rowStart, int* __restrict__ colIdx,
                        int N, int R, int E, int CHP) {
  __shared__ int offRow[NB_P];
  __shared__ int loffCol[NB_P];
  __shared__ int sc[512];
  __shared__ int stg[STG_CAP];
  const int b = (blockIdx.x & (NGRP - 1)) * (NBKT / NGRP) + (blockIdx.x >> 3);
  const int lo = bucketBase[b], hi = bucketBase[b + 1];
  const int cntB = hi - lo;
  const int nodeLo = b * R;
  const int nN = min(R, N - nodeLo);
  const int t = threadIdx.x;
  if (t < NB_P) {
    offRow[t] = off[b * NB_P + t];
    loffCol[t] = loffG[t * NBKT + b];
  }
  if (t < 512) sc[t] = 0;
  __syncthreads();
  auto fetch = [&](int i) -> int {
    int loQ = 0, hiQ = NB_P;
#pragma unroll
    for (int it = 0; it < 9; ++it) {
      int mid = (loQ + hiQ) >> 1;
      if (offRow[mid] <= i) loQ = mid; else hiQ = mid;
    }
    return epkPriv[(size_t)loQ * CHP + loffCol[loQ] + (i - offRow[loQ])];
  };
  for (int i = t; i < cntB; i += SORT_T) {
    int pk = fetch(i);
    atomicAdd(&sc[pk >> 17], 1);
  }
  __syncthreads();
  int own = (t < 512) ? sc[t] : 0;
  for (int o = 1; o < 512; o <<= 1) {
    int u = (t < 512 && t >= o) ? sc[t - o] : 0;
    __syncthreads();
    if (t < 512) sc[t] += u;
    __syncthreads();
  }
  if (t < nN) rowStart[nodeLo + t] = lo + sc[t] - own;
  if (b == NBKT - 1 && t == 0) rowStart[N] = E;
  if (t < 512) sc[t] -= own;
  __syncthreads();
  for (int i = t; i < cntB; i += SORT_T) {
    int pk = fetch(i);   // L2-hot second gather
    int pos = atomicAdd(&sc[pk >> 17], 1);
    stg[pos] = pk & 0x1FFFF;
  }
  __syncthreads();
  for (int i = t; i < cntB; i += SORT_T) colIdx[lo + i] = stg[i];  // coalesced
}

// ================= edge layer 1 + fused node transform 2 =================
// L=2 x 16B h1 gathers, S=4, masked chunks; colIdx software-pipelined.

__global__ void k_edge12(const int* __restrict__ rowStart, const int* __restrict__ colIdx,
                         const _Float16* __restrict__ h1, const float* __restrict__ as_,
                         const float* __restrict__ ad_, const float* __restrict__ b1,
                         const float* __restrict__ W2, const float* __restrict__ as2w,
                         const float* __restrict__ ad2w, Rec2* __restrict__ r2,
                         float* __restrict__ ad2, int N, int R8) {
  constexpr int L = 2, S = 4, LS = 8, NPB = TB / LS;
  __shared__ float Ws2[128], A2s[8], A2d[8], B1s[16];
  if (threadIdx.x < 128) Ws2[threadIdx.x] = W2[threadIdx.x];
  if (threadIdx.x < 8) {
    A2s[threadIdx.x] = as2w[threadIdx.x];
    A2d[threadIdx.x] = ad2w[threadIdx.x];
  }
  if (threadIdx.x < 16) B1s[threadIdx.x] = b1[threadIdx.x];
  __syncthreads();
  const int g = blockIdx.x & (NGRP - 1);
  const int lb = blockIdx.x / NGRP;
  const int lane = threadIdx.x % LS;
  const int sub = lane >> 1;
  const int j = lane & 1;
  const int n = g * R8 + lb * NPB + threadIdx.x / LS;
  const int nEnd = min((g + 1) * R8, N);
  if (n >= nEnd) return;
  const float adv = ad_[n * 2 + j];
  const int start = rowStart[n];
  const int end = rowStart[n + 1];
  float s = 0.f, acc[8];
#pragma unroll
  for (int q = 0; q < 8; ++q) acc[q] = 0.f;
  if (sub == 0) {  // self-loop
    float p = __expf(leaky(as_[n * 2 + j] + adv));
    h8v a0 = reinterpret_cast<const h8v*>(h1 + (size_t)n * 16)[j];
    s = p;
#pragma unroll
    for (int q = 0; q < 8; ++q) acc[q] = p * (float)a0[q];
  }
  const int base = start & ~3;
  const int nch = (end - base + 3) >> 2;
  i4v cv;
  if (sub < nch) cv = *reinterpret_cast<const i4v*>(colIdx + base + 4 * sub);
  for (int t = sub; t < nch; t += S) {
    i4v nxt = cv;
    if (t + S < nch) nxt = *reinterpret_cast<const i4v*>(colIdx + base + 4 * (t + S));
    const int i0 = base + 4 * t;
#pragma unroll
    for (int k = 0; k < 4; ++k) {
      const bool ok = (i0 + k >= start) && (i0 + k < end);
      const int src = ok ? cv[k] : n;
      h8v hv = reinterpret_cast<const h8v*>(h1 + (size_t)src * 16)[j];
      float e = as_[src * 2 + j];
      float p = ok ? __expf(leaky(e + adv)) : 0.f;
      s += p;
#pragma unroll
      for (int q = 0; q < 8; ++q) acc[q] += p * (float)hv[q];
    }
    cv = nxt;
  }
#pragma unroll
  for (int off = L; off < LS; off <<= 1) {
    s += __shfl_xor(s, off);
#pragma unroll
    for (int q = 0; q < 8; ++q) acc[q] += __shfl_xor(acc[q], off);
  }
  if (sub == 0) {
    float inv = 1.f / (s + 1e-16f);
    float o1v[8];
#pragma unroll
    for (int q = 0; q < 8; ++q) o1v[q] = fmaxf(acc[q] * inv + B1s[j * 8 + q], 0.f);
    float h2p[8];
#pragma unroll
    for (int q = 0; q < 8; ++q) {
      float tacc = 0.f;
#pragma unroll
      for (int c = 0; c < 8; ++c) tacc += o1v[c] * Ws2[(j * 8 + c) * 8 + q];
      h2p[q] = tacc;
    }
    float h2f[8];
#pragma unroll
    for (int q = 0; q < 8; ++q) h2f[q] = h2p[q] + __shfl_xor(h2p[q], 1);
    h4v v;
#pragma unroll
    for (int q = 0; q < 4; ++q) v[q] = (_Float16)h2f[j * 4 + q];
    reinterpret_cast<h4v*>(r2[n].h)[j] = v;
    float ss = 0.f, dd = 0.f;
#pragma unroll
    for (int c = 0; c < 4; ++c) {
      ss += h2f[j * 4 + c] * A2s[j * 4 + c];
      dd += h2f[j * 4 + c] * A2d[j * 4 + c];
    }
    r2[n].as[j] = ss;
    ad2[n * 2 + j] = dd;
  }
}

// ================= edge layer 2 + fused node transform 3 =================

__global__ void k_edge23(const int* __restrict__ rowStart, const int* __restrict__ colIdx,
                         const Rec2* __restrict__ r2, const float* __restrict__ ad_,
                         const float* __restrict__ b2, const float* __restrict__ W3,
                         const float* __restrict__ as3w, const float* __restrict__ ad3w,
                         Rec3* __restrict__ r3, float* __restrict__ ad3, int N, int R8) {
  constexpr int L = 2, S = 4, LS = 8, NPB = TB / LS;
  __shared__ float Ws3[32], A3s[4], A3d[4], B2s[8];
  if (threadIdx.x < 32) Ws3[threadIdx.x] = W3[threadIdx.x];
  if (threadIdx.x < 4) {
    A3s[threadIdx.x] = as3w[threadIdx.x];
    A3d[threadIdx.x] = ad3w[threadIdx.x];
  }
  if (threadIdx.x < 8) B2s[threadIdx.x] = b2[threadIdx.x];
  __syncthreads();
  const int g = blockIdx.x & (NGRP - 1);
  const int lb = blockIdx.x / NGRP;
  const int lane = threadIdx.x % LS;
  const int sub = lane >> 1;
  const int j = lane & 1;
  const int n = g * R8 + lb * NPB + threadIdx.x / LS;
  const int nEnd = min((g + 1) * R8, N);
  if (n >= nEnd) return;
  const float adv = ad_[n * 2 + j];
  const int start = rowStart[n];
  const int end = rowStart[n + 1];
  float s = 0.f, acc[4];
#pragma unroll
  for (int q = 0; q < 4; ++q) acc[q] = 0.f;
  if (sub == 0) {
    float p = __expf(leaky(r2[n].as[j] + adv));
    h4v a0 = reinterpret_cast<const h4v*>(r2[n].h)[j];
    s = p;
#pragma unroll
    for (int q = 0; q < 4; ++q) acc[q] = p * (float)a0[q];
  }
  const int base = start & ~3;
  const int nch = (end - base + 3) >> 2;
  i4v cv;
  if (sub < nch) cv = *reinterpret_cast<const i4v*>(colIdx + base + 4 * sub);
  for (int t = sub; t < nch; t += S) {
    i4v nxt = cv;
    if (t + S < nch) nxt = *reinterpret_cast<const i4v*>(colIdx + base + 4 * (t + S));
    const int i0 = base + 4 * t;
#pragma unroll
    for (int k = 0; k < 4; ++k) {
      const bool ok = (i0 + k >= start) && (i0 + k < end);
      const int src = ok ? cv[k] : n;
      h4v hv = reinterpret_cast<const h4v*>(r2[src].h)[j];
      float e = r2[src].as[j];
      float p = ok ? __expf(leaky(e + adv)) : 0.f;
      s += p;
#pragma unroll
      for (int q = 0; q < 4; ++q) acc[q] += p * (float)hv[q];
    }
    cv = nxt;
  }
#pragma unroll
  for (int off = L; off < LS; off <<= 1) {
    s += __shfl_xor(s, off);
#pragma unroll
    for (int q = 0; q < 4; ++q) acc[q] += __shfl_xor(acc[q], off);
  }
  if (sub == 0) {
    float inv = 1.f / (s + 1e-16f);
    float o2v[4];
#pragma unroll
    for (int q = 0; q < 4; ++q) o2v[q] = fmaxf(acc[q] * inv + B2s[j * 4 + q], 0.f);
    float h3p[4];
#pragma unroll
    for (int q = 0; q < 4; ++q) {
      float tacc = 0.f;
#pragma unroll
      for (int c = 0; c < 4; ++c) tacc += o2v[c] * Ws3[(j * 4 + c) * 4 + q];
      h3p[q] = tacc;
    }
    float h3f[4];
#pragma unroll
    for (int q = 0; q < 4; ++q) h3f[q] = h3p[q] + __shfl_xor(h3p[q], 1);
    if (j == 0) {
      Rec3 rec;
#pragma unroll
      for (int q = 0; q < 4; ++q) rec.h[q] = (_Float16)h3f[q];
      float ss = 0.f, dd = 0.f;
#pragma unroll
      for (int c = 0; c < 4; ++c) {
        ss += h3f[c] * A3s[c];
        dd += h3f[c] * A3d[c];
      }
      rec.as = ss;
      rec.pad = 0.f;
      r3[n] = rec;
      ad3[n] = dd;
    }
  }
}

// ================= edge layer 3 + fused classifier; S=8 =================

__global__ void k_edge3(const int* __restrict__ rowStart, const int* __restrict__ colIdx,
                        const Rec3* __restrict__ r3, const float* __restrict__ ad_,
                        const float* __restrict__ b3, const float* __restrict__ Wc,
                        const float* __restrict__ bc, float* __restrict__ out,
                        int N, int R8) {
  constexpr int S = 8;
  constexpr int NPB = TB / S;
  const int g = blockIdx.x & (NGRP - 1);
  const int lb = blockIdx.x / NGRP;
  const int sub = threadIdx.x % S;
  const int n = g * R8 + lb * NPB + threadIdx.x / S;
  const int nEnd = min((g + 1) * R8, N);
  if (n >= nEnd) return;
  const float adv = ad_[n];
  const int start = rowStart[n];
  const int end = rowStart[n + 1];
  float s = 0.f, acc0 = 0.f, acc1 = 0.f, acc2 = 0.f, acc3 = 0.f;
  if (sub == 0) {
    Rec3 rec = r3[n];
    float p = __expf(leaky(rec.as + adv));
    s = p;
    acc0 = p * (float)rec.h[0];
    acc1 = p * (float)rec.h[1];
    acc2 = p * (float)rec.h[2];
    acc3 = p * (float)rec.h[3];
  }
  const int base = start & ~3;
  const int nch = (end - base + 3) >> 2;
  i4v cv;
  if (sub < nch) cv = *reinterpret_cast<const i4v*>(colIdx + base + 4 * sub);
  for (int t = sub; t < nch; t += S) {
    i4v nxt = cv;
    if (t + S < nch) nxt = *reinterpret_cast<const i4v*>(colIdx + base + 4 * (t + S));
    const int i0 = base + 4 * t;
#pragma unroll
    for (int k = 0; k < 4; ++k) {
      const bool ok = (i0 + k >= start) && (i0 + k < end);
      const int src = ok ? cv[k] : n;
      Rec3 rec = r3[src];
      float p = ok ? __expf(leaky(rec.as + adv)) : 0.f;
      s += p;
      acc0 += p * (float)rec.h[0];
      acc1 += p * (float)rec.h[1];
      acc2 += p * (float)rec.h[2];
      acc3 += p * (float)rec.h[3];
    }
    cv = nxt;
  }
#pragma unroll
  for (int off = 1; off < S; off <<= 1) {
    s += __shfl_xor(s, off);
    acc0 += __shfl_xor(acc0, off);
    acc1 += __shfl_xor(acc1, off);
    acc2 += __shfl_xor(acc2, off);
    acc3 += __shfl_xor(acc3, off);
  }
  if (sub == 0) {
    float inv = 1.f / (s + 1e-16f);
    float o0 = acc0 * inv + b3[0];
    float o1 = acc1 * inv + b3[1];
    float o2 = acc2 * inv + b3[2];
    float o3 = acc3 * inv + b3[3];
    float2 r;
    r.x = o0 * Wc[0] + o1 * Wc[2] + o2 * Wc[4] + o3 * Wc[6] + bc[0];
    r.y = o0 * Wc[1] + o1 * Wc[3] + o2 * Wc[5] + o3 * Wc[7] + bc[1];
    reinterpret_cast<float2*>(out)[n] = r;
  }
}

// ================= launch =================

extern "C" void kernel_launch(void* const* d_in, const int* in_sizes, int n_in,
                              void* d_out, int out_size, void* d_ws, size_t ws_size,
                              hipStream_t stream) {
  const float* x    = (const float*)d_in[0];
  const int*   ei   = (const int*)d_in[1];
  const float* W1   = (const float*)d_in[2];
  const float* as1w = (const float*)d_in[3];
  const float* ad1w = (const float*)d_in[4];
  const float* b1   = (const float*)d_in[5];
  const float* W2   = (const float*)d_in[6];
  const float* as2w = (const float*)d_in[7];
  const float* ad2w = (const float*)d_in[8];
  const float* b2   = (const float*)d_in[9];
  const float* W3   = (const float*)d_in[10];
  const float* as3w = (const float*)d_in[11];
  const float* ad3w = (const float*)d_in[12];
  const float* b3   = (const float*)d_in[13];
  const float* Wc   = (const float*)d_in[14];
  const float* bc   = (const float*)d_in[15];
  float* out = (float*)d_out;

  const int N = in_sizes[0] / 128;
  const int E = in_sizes[1] / 2;
  const int* srcA = ei;
  const int* dstA = ei + E;

  char* p = (char*)d_ws;
  auto alloc = [&](size_t bytes) -> void* {
    void* r = (void*)p;
    p += (bytes + 255) & ~(size_t)255;
    return r;
  };
  const int E4  = E >> 2;
  const int CH4 = (E4 + NB_P - 1) / NB_P;
  const int CHP = CH4 * 4 + 8;

  int* cnt        = (int*)alloc((size_t)NBKT * NB_P * 4);
  int* off        = (int*)alloc((size_t)NBKT * NB_P * 4);
  int* loffG      = (int*)alloc((size_t)NB_P * NBKT * 4);
  int* colTotal   = (int*)alloc(NBKT * 4);
  int* bucketBase = (int*)alloc((NBKT + 1) * 4);
  int* rowStart   = (int*)alloc((size_t)(N + 1) * 4);
  int* epkPriv    = (int*)alloc((size_t)NB_P * CHP * 4);
  int* colIdx     = (int*)alloc((size_t)E * 4 + 256);
  _Float16* h1 = (_Float16*)alloc((size_t)N * 16 * 2);
  float* as1 = (float*)alloc((size_t)N * 2 * 4);
  float* ad1 = (float*)alloc((size_t)N * 2 * 4);
  Rec2* r2   = (Rec2*)alloc((size_t)N * sizeof(Rec2));
  float* ad2 = (float*)alloc((size_t)N * 2 * 4);
  Rec3* r3   = (Rec3*)alloc((size_t)N * sizeof(Rec3));
  float* ad3 = (float*)alloc((size_t)N * 4);

  const int R   = (N + NBKT - 1) / NBKT;                       // nodes per bucket (391)
  const unsigned M = (unsigned)(((1ULL << 32) + R - 1) / R);   // exact /R via __umulhi
  const int R8  = R * (NBKT / NGRP);                           // nodes per XCD (12512)

  const int nb1 = (N + (TB / 4) - 1) / (TB / 4);   // node1 blocks (SPLIT=4)
  const int ge8 = NGRP * ((R8 + (TB / 8) - 1) / (TB / 8));  // 32 nodes/block

  // single-pass CSR scatter + node1 overlapped in the first dispatch
  k_scatter_node1<<<NB_P + nb1, TB, 0, stream>>>(srcA, dstA, cnt, loffG, epkPriv,
                                                 E4, E, M, R, CH4, CHP,
                                                 x, W1, as1w, ad1w, h1, as1, ad1, N);
  k_bscan1<<<NBKT, NB_P, 0, stream>>>(cnt, off, colTotal);
  k_bscan2<<<1, NBKT, 0, stream>>>(colTotal, bucketBase);
  k_bsort<<<NBKT, SORT_T, 0, stream>>>(epkPriv, off, loffG, bucketBase, rowStart,
                                       colIdx, N, R, E, CHP);

  k_edge12<<<ge8, TB, 0, stream>>>(rowStart, colIdx, h1, as1, ad1, b1, W2, as2w, ad2w,
                                   r2, ad2, N, R8);
  k_edge23<<<ge8, TB, 0, stream>>>(rowStart, colIdx, r2, ad2, b2, W3, as3w, ad3w,
                                   r3, ad3, N, R8);
  k_edge3<<<ge8, TB, 0, stream>>>(rowStart, colIdx, r3, ad3, b3, Wc, bc, out, N, R8);
}

// Round 15
// 160.870 us; speedup vs baseline: 1.2715x; 1.0494x over previous
//
#include <hip/hip_runtime.h>

#define TB 256
#define NGRP 8            // XCDs on MI355X
#define NB_P 1024         // partition blocks
#define TBP 256           // partition block threads
#define NBKT 256          // dst-range buckets (32 per XCD)
#define SORT_T 1024
#define STG_CAP 13312     // LDS staging entries in k_bsort
#define STG2_CAP 3200     // LDS staging entries in k_scatter
#define RCAP 4            // register-cached int4 chunks per thread in scatter

typedef int      i4v __attribute__((ext_vector_type(4)));
typedef float    f4v __attribute__((ext_vector_type(4)));
typedef _Float16 h4v __attribute__((ext_vector_type(4)));
typedef _Float16 h8v __attribute__((ext_vector_type(8)));

// Packed gather records: one cache line fetch per edge.
struct __align__(16) Rec2 { _Float16 h[8]; float as[2]; float pad[2]; };  // 32 B
struct __align__(16) Rec3 { _Float16 h[4]; float as; float pad; };        // 16 B

static __device__ __forceinline__ float leaky(float x) {
  return x > 0.f ? x : 0.2f * x;
}

// ========== fused single-pass scatter + node1 ==========
// Blocks [0,NB_P): read own edge chunk ONCE (cached in registers), LDS
// counting-sort by bucket, coalesced flush to block-private epkPriv; emit
// cnt + local offsets. Blocks [NB_P,...): layer-1 node transform x@W1.

__global__ void __launch_bounds__(TB)
k_scatter_node1(const int* __restrict__ srcA, const int* __restrict__ dstA,
                int* __restrict__ cnt, int* __restrict__ loffG,
                int* __restrict__ epkPriv, int E4, int E, unsigned M, int R,
                int CH4, int CHP,
                const float* __restrict__ xin, const float* __restrict__ W1,
                const float* __restrict__ a_src, const float* __restrict__ a_dst,
                _Float16* __restrict__ hout, float* __restrict__ ad_, int N) {
  __shared__ __align__(16) char smem[18960];
  const int t = threadIdx.x;
  if (blockIdx.x < NB_P) {
    const int kblk = blockIdx.x;
    int* lc   = (int*)smem;                 // 4*NBKT sub-histograms (4 KB)
    int* loff = (int*)(smem + 4096);        // NBKT+1
    int* lcur = (int*)(smem + 5136);        // NBKT
    int* stg  = (int*)(smem + 6160);        // STG2_CAP
    for (int i = t; i < 4 * NBKT; i += TBP) lc[i] = 0;
    __syncthreads();
    int* lcw = lc + (t >> 6) * NBKT;
    const int bstart = kblk * CH4;
    const int bend = min(E4, bstart + CH4);
    const i4v* d4 = reinterpret_cast<const i4v*>(dstA);
    const i4v* s4 = reinterpret_cast<const i4v*>(srcA);
    i4v dr[RCAP], sr[RCAP];
    // pass 1: load chunk into registers + histogram
    int it1 = 0;
    for (int i = bstart + t; i < bend; i += TBP, ++it1) {
      i4v d = __builtin_nontemporal_load(&d4[i]);
      i4v sv = __builtin_nontemporal_load(&s4[i]);
      if (it1 < RCAP) { dr[it1] = d; sr[it1] = sv; }
#pragma unroll
      for (int k = 0; k < 4; ++k) atomicAdd(&lcw[__umulhi((unsigned)d[k], M)], 1);
    }
    if (kblk == NB_P - 1) {
      for (int i = E4 * 4 + t; i < E; i += TBP)
        atomicAdd(&lcw[__umulhi((unsigned)dstA[i], M)], 1);
    }
    __syncthreads();
    // reduce sub-hists + exclusive scan -> local layout; emit cnt, loffG
    int c = 0;
    if (t < NBKT) {
      c = lc[t] + lc[NBKT + t] + lc[2 * NBKT + t] + lc[3 * NBKT + t];
      loff[t] = c;
    }
    __syncthreads();
    for (int o = 1; o < NBKT; o <<= 1) {
      int u = (t < NBKT && t >= o) ? loff[t - o] : 0;
      __syncthreads();
      if (t < NBKT) loff[t] += u;
      __syncthreads();
    }
    if (t < NBKT) {
      int excl = loff[t] - c;
      cnt[t * NB_P + kblk] = c;          // [bucket][block] for bscan1
      loffG[kblk * NBKT + t] = excl;     // block-major local offsets
      lcur[t] = excl;
      loff[t] = excl;
      if (t == NBKT - 1) loff[NBKT] = excl + c;
    }
    __syncthreads();
    // pass 2: scatter packed edges into LDS by bucket (from registers)
    int it2 = 0;
    for (int i = bstart + t; i < bend; i += TBP, ++it2) {
      i4v d = (it2 < RCAP) ? dr[it2] : d4[i];
      i4v sv = (it2 < RCAP) ? sr[it2] : s4[i];
#pragma unroll
      for (int k = 0; k < 4; ++k) {
        int dd = d[k];
        int b = __umulhi((unsigned)dd, M);
        int pos = atomicAdd(&lcur[b], 1);
        stg[pos] = ((dd - b * R) << 17) | sv[k];
      }
    }
    if (kblk == NB_P - 1) {
      for (int i = E4 * 4 + t; i < E; i += TBP) {
        int dd = dstA[i];
        int b = __umulhi((unsigned)dd, M);
        int pos = atomicAdd(&lcur[b], 1);
        stg[pos] = ((dd - b * R) << 17) | srcA[i];
      }
    }
    __syncthreads();
    // linear coalesced flush to private region
    const int total = loff[NBKT];
    int* dst = epkPriv + (size_t)kblk * CHP;
    for (int i = t; i < total; i += TBP) dst[i] = stg[i];
  } else {
    // ---- node transform layer 1: IN=128, H=2, C=8, SPLIT=4 ----
    constexpr int IN = 128, OUT = 16, SPLIT = 4, NPB = TB / SPLIT, PIN4 = IN / SPLIT / 4;
    float* Ws = (float*)smem;
    float* Ad = (float*)(smem + 8192);
    const int bid = blockIdx.x - NB_P;
    for (int i = t; i < IN * OUT; i += TB) Ws[i] = W1[i];
    if (t < OUT) Ad[t] = a_dst[t];
    __syncthreads();
    const int j = t & (SPLIT - 1);
    const int n = bid * NPB + t / SPLIT;
    if (n >= N) return;
    float acc[OUT];
#pragma unroll
    for (int q = 0; q < OUT; ++q) acc[q] = 0.f;
    const f4v* x4 = reinterpret_cast<const f4v*>(xin + (size_t)n * IN + j * (IN / SPLIT));
#pragma unroll
    for (int k4 = 0; k4 < PIN4; ++k4) {
      f4v xv = __builtin_nontemporal_load(&x4[k4]);
      const int kb = j * (IN / SPLIT) + 4 * k4;
#pragma unroll
      for (int q = 0; q < OUT; ++q) {
        acc[q] += xv[0] * Ws[(kb + 0) * OUT + q];
        acc[q] += xv[1] * Ws[(kb + 1) * OUT + q];
        acc[q] += xv[2] * Ws[(kb + 2) * OUT + q];
        acc[q] += xv[3] * Ws[(kb + 3) * OUT + q];
      }
    }
#pragma unroll
    for (int o = 1; o < SPLIT; o <<= 1) {
#pragma unroll
      for (int q = 0; q < OUT; ++q) acc[q] += __shfl_xor(acc[q], o);
    }
    if (j < OUT / 4) {
      h4v v;
      v[0] = (_Float16)acc[4 * j + 0];
      v[1] = (_Float16)acc[4 * j + 1];
      v[2] = (_Float16)acc[4 * j + 2];
      v[3] = (_Float16)acc[4 * j + 3];
      reinterpret_cast<h4v*>(hout + (size_t)n * OUT)[j] = v;
    }
    if (j < 2) {
      float dd = 0.f;
#pragma unroll
      for (int c = 0; c < 8; ++c) dd += acc[j * 8 + c] * Ad[j * 8 + c];
      ad_[n * 2 + j] = dd;
    }
  }
}

// A2a: per-bucket exclusive scan over blocks (grid = NBKT, block = NB_P threads).
__global__ void k_bscan1(const int* __restrict__ cnt, int* __restrict__ off,
                         int* __restrict__ colTotal) {
  __shared__ int sh[NB_P];
  const int t = threadIdx.x;
  const int b = blockIdx.x;
  int v = cnt[b * NB_P + t];
  sh[t] = v;
  __syncthreads();
  for (int o = 1; o < NB_P; o <<= 1) {
    int u = (t >= o) ? sh[t - o] : 0;
    __syncthreads();
    sh[t] += u;
    __syncthreads();
  }
  off[b * NB_P + t] = sh[t] - v;
  if (t == NB_P - 1) colTotal[b] = sh[t];
}

// A2b: exclusive scan of bucket totals -> bucketBase[NBKT+1].
__global__ void k_bscan2(const int* __restrict__ colTotal, int* __restrict__ bucketBase) {
  __shared__ int sh[NBKT];
  const int t = threadIdx.x;
  int v = colTotal[t];
  sh[t] = v;
  __syncthreads();
  for (int o = 1; o < NBKT; o <<= 1) {
    int u = (t >= o) ? sh[t - o] : 0;
    __syncthreads();
    sh[t] += u;
    __syncthreads();
  }
  bucketBase[t] = sh[t] - v;
  if (t == NBKT - 1) bucketBase[NBKT] = sh[t];
}

// B: per-bucket counting sort; gather from block-private runs via binary
// search; LDS staging; coalesced colIdx write (fallback if bucket > cap).
__global__ void k_bsort(const int* __restrict__ epkPriv, const int* __restrict__ off,
                        const int* __restrict__ loffG, const int* __restrict__ bucketBase,
                        int* __restrict__ rowStart, int* __restrict__ colIdx,
                        int N, int R, int E, int CHP) {
  __shared__ int offRow[NB_P];
  __shared__ int loffCol[NB_P];
  __shared__ int sc[512];
  __shared__ int stg[STG_CAP];
  const int b = (blockIdx.x & (NGRP - 1)) * (NBKT / NGRP) + (blockIdx.x >> 3);
  const int lo = bucketBase[b], hi = bucketBase[b + 1];
  const int cntB = hi - lo;
  const int nodeLo = b * R;
  const int nN = min(R, N - nodeLo);
  const int t = threadIdx.x;
  for (int i = t; i < NB_P; i += SORT_T) {
    offRow[i] = off[b * NB_P + i];
    loffCol[i] = loffG[i * NBKT + b];
  }
  if (t < 512) sc[t] = 0;
  __syncthreads();
  auto fetch = [&](int i) -> int {
    int loQ = 0, hiQ = NB_P;
#pragma unroll
    for (int it = 0; it < 10; ++it) {
      int mid = (loQ + hiQ) >> 1;
      if (offRow[mid] <= i) loQ = mid; else hiQ = mid;
    }
    return epkPriv[(size_t)loQ * CHP + loffCol[loQ] + (i - offRow[loQ])];
  };
  for (int i = t; i < cntB; i += SORT_T) {
    int pk = fetch(i);
    atomicAdd(&sc[pk >> 17], 1);
  }
  __syncthreads();
  int own = (t < 512) ? sc[t] : 0;
  for (int o = 1; o < 512; o <<= 1) {
    int u = (t < 512 && t >= o) ? sc[t - o] : 0;
    __syncthreads();
    if (t < 512) sc[t] += u;
    __syncthreads();
  }
  if (t < nN) rowStart[nodeLo + t] = lo + sc[t] - own;
  if (b == NBKT - 1 && t == 0) rowStart[N] = E;
  if (t < 512) sc[t] -= own;
  __syncthreads();
  if (cntB <= STG_CAP) {
    for (int i = t; i < cntB; i += SORT_T) {
      int pk = fetch(i);   // L2-hot second gather
      int pos = atomicAdd(&sc[pk >> 17], 1);
      stg[pos] = pk & 0x1FFFF;
    }
    __syncthreads();
    for (int i = t; i < cntB; i += SORT_T) colIdx[lo + i] = stg[i];  // coalesced
  } else {
    for (int i = t; i < cntB; i += SORT_T) {
      int pk = fetch(i);
      int pos = lo + atomicAdd(&sc[pk >> 17], 1);
      colIdx[pos] = pk & 0x1FFFF;
    }
  }
}

// ================= edge layer 1 + fused node transform 2 =================
// L=2 x 16B h1 gathers, S=4, masked chunks; colIdx software-pipelined.
// as recomputed in-register from gathered h (dot with a_src) -> 1 line/edge.

__global__ void k_edge12(const int* __restrict__ rowStart, const int* __restrict__ colIdx,
                         const _Float16* __restrict__ h1, const float* __restrict__ as1w,
                         const float* __restrict__ ad_, const float* __restrict__ b1,
                         const float* __restrict__ W2, const float* __restrict__ as2w,
                         const float* __restrict__ ad2w, Rec2* __restrict__ r2,
                         float* __restrict__ ad2, int N, int R8) {
  constexpr int L = 2, S = 4, LS = 8, NPB = TB / LS;
  __shared__ float Ws2[128], A1s[16], A2s[8], A2d[8], B1s[16];
  if (threadIdx.x < 128) Ws2[threadIdx.x] = W2[threadIdx.x];
  if (threadIdx.x < 16) {
    A1s[threadIdx.x] = as1w[threadIdx.x];
    B1s[threadIdx.x] = b1[threadIdx.x];
  }
  if (threadIdx.x < 8) {
    A2s[threadIdx.x] = as2w[threadIdx.x];
    A2d[threadIdx.x] = ad2w[threadIdx.x];
  }
  __syncthreads();
  const int g = blockIdx.x & (NGRP - 1);
  const int lb = blockIdx.x / NGRP;
  const int lane = threadIdx.x % LS;
  const int sub = lane >> 1;
  const int j = lane & 1;
  const int n = g * R8 + lb * NPB + threadIdx.x / LS;
  const int nEnd = min((g + 1) * R8, N);
  if (n >= nEnd) return;
  const float adv = ad_[n * 2 + j];
  float aw[8];
#pragma unroll
  for (int c = 0; c < 8; ++c) aw[c] = A1s[j * 8 + c];
  const int start = rowStart[n];
  const int end = rowStart[n + 1];
  float s = 0.f, acc[8];
#pragma unroll
  for (int q = 0; q < 8; ++q) acc[q] = 0.f;
  if (sub == 0) {  // self-loop
    h8v a0 = reinterpret_cast<const h8v*>(h1 + (size_t)n * 16)[j];
    float e = 0.f;
#pragma unroll
    for (int c = 0; c < 8; ++c) e += (float)a0[c] * aw[c];
    float p = __expf(leaky(e + adv));
    s = p;
#pragma unroll
    for (int q = 0; q < 8; ++q) acc[q] = p * (float)a0[q];
  }
  const int base = start & ~3;
  const int nch = (end - base + 3) >> 2;
  i4v cv;
  if (sub < nch) cv = *reinterpret_cast<const i4v*>(colIdx + base + 4 * sub);
  for (int t = sub; t < nch; t += S) {
    i4v nxt = cv;
    if (t + S < nch) nxt = *reinterpret_cast<const i4v*>(colIdx + base + 4 * (t + S));
    const int i0 = base + 4 * t;
#pragma unroll
    for (int k = 0; k < 4; ++k) {
      const bool ok = (i0 + k >= start) && (i0 + k < end);
      const int src = ok ? cv[k] : n;
      h8v hv = reinterpret_cast<const h8v*>(h1 + (size_t)src * 16)[j];
      float e = 0.f;
#pragma unroll
      for (int c = 0; c < 8; ++c) e += (float)hv[c] * aw[c];
      float p = ok ? __expf(leaky(e + adv)) : 0.f;
      s += p;
#pragma unroll
      for (int q = 0; q < 8; ++q) acc[q] += p * (float)hv[q];
    }
    cv = nxt;
  }
#pragma unroll
  for (int off = L; off < LS; off <<= 1) {
    s += __shfl_xor(s, off);
#pragma unroll
    for (int q = 0; q < 8; ++q) acc[q] += __shfl_xor(acc[q], off);
  }
  if (sub == 0) {
    float inv = 1.f / (s + 1e-16f);
    float o1v[8];
#pragma unroll
    for (int q = 0; q < 8; ++q) o1v[q] = fmaxf(acc[q] * inv + B1s[j * 8 + q], 0.f);
    float h2p[8];
#pragma unroll
    for (int q = 0; q < 8; ++q) {
      float tacc = 0.f;
#pragma unroll
      for (int c = 0; c < 8; ++c) tacc += o1v[c] * Ws2[(j * 8 + c) * 8 + q];
      h2p[q] = tacc;
    }
    float h2f[8];
#pragma unroll
    for (int q = 0; q < 8; ++q) h2f[q] = h2p[q] + __shfl_xor(h2p[q], 1);
    h4v v;
#pragma unroll
    for (int q = 0; q < 4; ++q) v[q] = (_Float16)h2f[j * 4 + q];
    reinterpret_cast<h4v*>(r2[n].h)[j] = v;
    float ss = 0.f, dd = 0.f;
#pragma unroll
    for (int c = 0; c < 4; ++c) {
      ss += h2f[j * 4 + c] * A2s[j * 4 + c];
      dd += h2f[j * 4 + c] * A2d[j * 4 + c];
    }
    r2[n].as[j] = ss;
    ad2[n * 2 + j] = dd;
  }
}

// ================= edge layer 2 + fused node transform 3 =================

__global__ void k_edge23(const int* __restrict__ rowStart, const int* __restrict__ colIdx,
                         const Rec2* __restrict__ r2, const float* __restrict__ ad_,
                         const float* __restrict__ b2, const float* __restrict__ W3,
                         const float* __restrict__ as3w, const float* __restrict__ ad3w,
                         Rec3* __restrict__ r3, float* __restrict__ ad3, int N, int R8) {
  constexpr int L = 2, S = 4, LS = 8, NPB = TB / LS;
  __shared__ float Ws3[32], A3s[4], A3d[4], B2s[8];
  if (threadIdx.x < 32) Ws3[threadIdx.x] = W3[threadIdx.x];
  if (threadIdx.x < 4) {
    A3s[threadIdx.x] = as3w[threadIdx.x];
    A3d[threadIdx.x] = ad3w[threadIdx.x];
  }
  if (threadIdx.x < 8) B2s[threadIdx.x] = b2[threadIdx.x];
  __syncthreads();
  const int g = blockIdx.x & (NGRP - 1);
  const int lb = blockIdx.x / NGRP;
  const int lane = threadIdx.x % LS;
  const int sub = lane >> 1;
  const int j = lane & 1;
  const int n = g * R8 + lb * NPB + threadIdx.x / LS;
  const int nEnd = min((g + 1) * R8, N);
  if (n >= nEnd) return;
  const float adv = ad_[n * 2 + j];
  const int start = rowStart[n];
  const int end = rowStart[n + 1];
  float s = 0.f, acc[4];
#pragma unroll
  for (int q = 0; q < 4; ++q) acc[q] = 0.f;
  if (sub == 0) {
    float p = __expf(leaky(r2[n].as[j] + adv));
    h4v a0 = reinterpret_cast<const h4v*>(r2[n].h)[j];
    s = p;
#pragma unroll
    for (int q = 0; q < 4; ++q) acc[q] = p * (float)a0[q];
  }
  const int base = start & ~3;
  const int nch = (end - base + 3) >> 2;
  i4v cv;
  if (sub < nch) cv = *reinterpret_cast<const i4v*>(colIdx + base + 4 * sub);
  for (int t = sub; t < nch; t += S) {
    i4v nxt = cv;
    if (t + S < nch) nxt = *reinterpret_cast<const i4v*>(colIdx + base + 4 * (t + S));
    const int i0 = base + 4 * t;
#pragma unroll
    for (int k = 0; k < 4; ++k) {
      const bool ok = (i0 + k >= start) && (i0 + k < end);
      const int src = ok ? cv[k] : n;
      h4v hv = reinterpret_cast<const h4v*>(r2[src].h)[j];
      float e = r2[src].as[j];
      float p = ok ? __expf(leaky(e + adv)) : 0.f;
      s += p;
#pragma unroll
      for (int q = 0; q < 4; ++q) acc[q] += p * (float)hv[q];
    }
    cv = nxt;
  }
#pragma unroll
  for (int off = L; off < LS; off <<= 1) {
    s += __shfl_xor(s, off);
#pragma unroll
    for (int q = 0; q < 4; ++q) acc[q] += __shfl_xor(acc[q], off);
  }
  if (sub == 0) {
    float inv = 1.f / (s + 1e-16f);
    float o2v[4];
#pragma unroll
    for (int q = 0; q < 4; ++q) o2v[q] = fmaxf(acc[q] * inv + B2s[j * 4 + q], 0.f);
    float h3p[4];
#pragma unroll
    for (int q = 0; q < 4; ++q) {
      float tacc = 0.f;
#pragma unroll
      for (int c = 0; c < 4; ++c) tacc += o2v[c] * Ws3[(j * 4 + c) * 4 + q];
      h3p[q] = tacc;
    }
    float h3f[4];
#pragma unroll
    for (int q = 0; q < 4; ++q) h3f[q] = h3p[q] + __shfl_xor(h3p[q], 1);
    if (j == 0) {
      Rec3 rec;
#pragma unroll
      for (int q = 0; q < 4; ++q) rec.h[q] = (_Float16)h3f[q];
      float ss = 0.f, dd = 0.f;
#pragma unroll
      for (int c = 0; c < 4; ++c) {
        ss += h3f[c] * A3s[c];
        dd += h3f[c] * A3d[c];
      }
      rec.as = ss;
      rec.pad = 0.f;
      r3[n] = rec;
      ad3[n] = dd;
    }
  }
}

// ================= edge layer 3 + fused classifier; S=8 =================

__global__ void k_edge3(const int* __restrict__ rowStart, const int* __restrict__ colIdx,
                        const Rec3* __restrict__ r3, const float* __restrict__ ad_,
                        const float* __restrict__ b3, const float* __restrict__ Wc,
                        const float* __restrict__ bc, float* __restrict__ out,
                        int N, int R8) {
  constexpr int S = 8;
  constexpr int NPB = TB / S;
  const int g = blockIdx.x & (NGRP - 1);
  const int lb = blockIdx.x / NGRP;
  const int sub = threadIdx.x % S;
  const int n = g * R8 + lb * NPB + threadIdx.x / S;
  const int nEnd = min((g + 1) * R8, N);
  if (n >= nEnd) return;
  const float adv = ad_[n];
  const int start = rowStart[n];
  const int end = rowStart[n + 1];
  float s = 0.f, acc0 = 0.f, acc1 = 0.f, acc2 = 0.f, acc3 = 0.f;
  if (sub == 0) {
    Rec3 rec = r3[n];
    float p = __expf(leaky(rec.as + adv));
    s = p;
    acc0 = p * (float)rec.h[0];
    acc1 = p * (float)rec.h[1];
    acc2 = p * (float)rec.h[2];
    acc3 = p * (float)rec.h[3];
  }
  const int base = start & ~3;
  const int nch = (end - base + 3) >> 2;
  i4v cv;
  if (sub < nch) cv = *reinterpret_cast<const i4v*>(colIdx + base + 4 * sub);
  for (int t = sub; t < nch; t += S) {
    i4v nxt = cv;
    if (t + S < nch) nxt = *reinterpret_cast<const i4v*>(colIdx + base + 4 * (t + S));
    const int i0 = base + 4 * t;
#pragma unroll
    for (int k = 0; k < 4; ++k) {
      const bool ok = (i0 + k >= start) && (i0 + k < end);
      const int src = ok ? cv[k] : n;
      Rec3 rec = r3[src];
      float p = ok ? __expf(leaky(rec.as + adv)) : 0.f;
      s += p;
      acc0 += p * (float)rec.h[0];
      acc1 += p * (float)rec.h[1];
      acc2 += p * (float)rec.h[2];
      acc3 += p * (float)rec.h[3];
    }
    cv = nxt;
  }
#pragma unroll
  for (int off = 1; off < S; off <<= 1) {
    s += __shfl_xor(s, off);
    acc0 += __shfl_xor(acc0, off);
    acc1 += __shfl_xor(acc1, off);
    acc2 += __shfl_xor(acc2, off);
    acc3 += __shfl_xor(acc3, off);
  }
  if (sub == 0) {
    float inv = 1.f / (s + 1e-16f);
    float o0 = acc0 * inv + b3[0];
    float o1 = acc1 * inv + b3[1];
    float o2 = acc2 * inv + b3[2];
    float o3 = acc3 * inv + b3[3];
    float2 r;
    r.x = o0 * Wc[0] + o1 * Wc[2] + o2 * Wc[4] + o3 * Wc[6] + bc[0];
    r.y = o0 * Wc[1] + o1 * Wc[3] + o2 * Wc[5] + o3 * Wc[7] + bc[1];
    reinterpret_cast<float2*>(out)[n] = r;
  }
}

// ================= launch =================

extern "C" void kernel_launch(void* const* d_in, const int* in_sizes, int n_in,
                              void* d_out, int out_size, void* d_ws, size_t ws_size,
                              hipStream_t stream) {
  const float* x    = (const float*)d_in[0];
  const int*   ei   = (const int*)d_in[1];
  const float* W1   = (const float*)d_in[2];
  const float* as1w = (const float*)d_in[3];
  const float* ad1w = (const float*)d_in[4];
  const float* b1   = (const float*)d_in[5];
  const float* W2   = (const float*)d_in[6];
  const float* as2w = (const float*)d_in[7];
  const float* ad2w = (const float*)d_in[8];
  const float* b2   = (const float*)d_in[9];
  const float* W3   = (const float*)d_in[10];
  const float* as3w = (const float*)d_in[11];
  const float* ad3w = (const float*)d_in[12];
  const float* b3   = (const float*)d_in[13];
  const float* Wc   = (const float*)d_in[14];
  const float* bc   = (const float*)d_in[15];
  float* out = (float*)d_out;

  const int N = in_sizes[0] / 128;
  const int E = in_sizes[1] / 2;
  const int* srcA = ei;
  const int* dstA = ei + E;

  char* p = (char*)d_ws;
  auto alloc = [&](size_t bytes) -> void* {
    void* r = (void*)p;
    p += (bytes + 255) & ~(size_t)255;
    return r;
  };
  const int E4  = E >> 2;
  const int CH4 = (E4 + NB_P - 1) / NB_P;
  const int CHP = CH4 * 4 + 8;

  int* cnt        = (int*)alloc((size_t)NBKT * NB_P * 4);
  int* off        = (int*)alloc((size_t)NBKT * NB_P * 4);
  int* loffG      = (int*)alloc((size_t)NB_P * NBKT * 4);
  int* colTotal   = (int*)alloc(NBKT * 4);
  int* bucketBase = (int*)alloc((NBKT + 1) * 4);
  int* rowStart   = (int*)alloc((size_t)(N + 1) * 4);
  int* epkPriv    = (int*)alloc((size_t)NB_P * CHP * 4);
  int* colIdx     = (int*)alloc((size_t)E * 4 + 256);
  _Float16* h1 = (_Float16*)alloc((size_t)N * 16 * 2);
  float* ad1 = (float*)alloc((size_t)N * 2 * 4);
  Rec2* r2   = (Rec2*)alloc((size_t)N * sizeof(Rec2));
  float* ad2 = (float*)alloc((size_t)N * 2 * 4);
  Rec3* r3   = (Rec3*)alloc((size_t)N * sizeof(Rec3));
  float* ad3 = (float*)alloc((size_t)N * 4);

  const int R   = (N + NBKT - 1) / NBKT;                       // nodes per bucket (391)
  const unsigned M = (unsigned)(((1ULL << 32) + R - 1) / R);   // exact /R via __umulhi
  const int R8  = R * (NBKT / NGRP);                           // nodes per XCD (12512)

  const int nb1 = (N + (TB / 4) - 1) / (TB / 4);   // node1 blocks (SPLIT=4)
  const int ge8 = NGRP * ((R8 + (TB / 8) - 1) / (TB / 8));  // 32 nodes/block

  // single-pass CSR scatter + node1 overlapped in the first dispatch
  k_scatter_node1<<<NB_P + nb1, TB, 0, stream>>>(srcA, dstA, cnt, loffG, epkPriv,
                                                 E4, E, M, R, CH4, CHP,
                                                 x, W1, as1w, ad1w, h1, ad1, N);
  k_bscan1<<<NBKT, NB_P, 0, stream>>>(cnt, off, colTotal);
  k_bscan2<<<1, NBKT, 0, stream>>>(colTotal, bucketBase);
  k_bsort<<<NBKT, SORT_T, 0, stream>>>(epkPriv, off, loffG, bucketBase, rowStart,
                                       colIdx, N, R, E, CHP);

  k_edge12<<<ge8, TB, 0, stream>>>(rowStart, colIdx, h1, as1w, ad1, b1, W2, as2w, ad2w,
                                   r2, ad2, N, R8);
  k_edge23<<<ge8, TB, 0, stream>>>(rowStart, colIdx, r2, ad2, b2, W3, as3w, ad3w,
                                   r3, ad3, N, R8);
  k_edge3<<<ge8, TB, 0, stream>>>(rowStart, colIdx, r3, ad3, b3, Wc, bc, out, N, R8);
}